// Round 1
// baseline (11206.521 us; speedup 1.0000x reference)
//
#include <hip/hip_runtime.h>

#define F_IN 512
#define F_OUT 256

// ---------------------------------------------------------------------------
// GEMM: h[n, 256] = x[n, 512] @ w[512, 256]   (fp32, vector ALU)
// Block = 256 threads, handles 32 rows. x-tile (32x512 fp32 = 64 KiB) in LDS.
// Thread t owns column c=t for all 32 rows (32 fp32 accumulators).
// ---------------------------------------------------------------------------
__global__ __launch_bounds__(256) void gemm_xw(const float* __restrict__ x,
                                               const float* __restrict__ w,
                                               float* __restrict__ h,
                                               int n_nodes) {
    __shared__ float xs[32 * F_IN];  // 64 KiB
    const int row0 = blockIdx.x * 32;
    const int t = threadIdx.x;
    const int rows_here = min(32, n_nodes - row0);

    // Cooperative load: 32*512 floats = 4096 float4, 16 per thread, coalesced.
    const float4* xg = reinterpret_cast<const float4*>(x + (size_t)row0 * F_IN);
    float4* xs4 = reinterpret_cast<float4*>(xs);
    if (rows_here == 32) {
#pragma unroll
        for (int i = 0; i < 16; ++i) {
            int idx = i * 256 + t;
            xs4[idx] = xg[idx];
        }
    } else {
        for (int i = 0; i < 16; ++i) {
            int idx = i * 256 + t;            // float4 index
            int r = idx >> 7;                 // / (512/4)
            if (r < rows_here) xs4[idx] = xg[idx];
        }
    }
    __syncthreads();

    const int c = t;  // output column 0..255
    float acc[32];
#pragma unroll
    for (int r = 0; r < 32; ++r) acc[r] = 0.f;

    for (int k = 0; k < F_IN; k += 4) {
        // W loads coalesced across threads (c contiguous).
        float wk0 = w[(size_t)(k + 0) * F_OUT + c];
        float wk1 = w[(size_t)(k + 1) * F_OUT + c];
        float wk2 = w[(size_t)(k + 2) * F_OUT + c];
        float wk3 = w[(size_t)(k + 3) * F_OUT + c];
#pragma unroll
        for (int r = 0; r < 32; ++r) {
            float4 xv = *reinterpret_cast<const float4*>(&xs[r * F_IN + k]);
            acc[r] = fmaf(xv.x, wk0, acc[r]);
            acc[r] = fmaf(xv.y, wk1, acc[r]);
            acc[r] = fmaf(xv.z, wk2, acc[r]);
            acc[r] = fmaf(xv.w, wk3, acc[r]);
        }
    }

#pragma unroll
    for (int r = 0; r < 32; ++r) {
        if (r < rows_here) h[(size_t)(row0 + r) * F_OUT + c] = acc[r];
    }
}

// ---------------------------------------------------------------------------
// SpMM scatter: out[rows[e]] += vals[e] * h[cols[e]]   (atomicAdd fp32)
// One wave (64 lanes) per edge; lane l handles float4 at feature 4*l.
// Each wave processes EDGES_PER_WAVE consecutive edges.
// ---------------------------------------------------------------------------
#define EDGES_PER_WAVE 32

__global__ __launch_bounds__(256) void spmm_scatter(const int* __restrict__ rows,
                                                    const int* __restrict__ cols,
                                                    const float* __restrict__ vals,
                                                    const float* __restrict__ h,
                                                    float* __restrict__ out,
                                                    int n_edges) {
    const int wave = (int)((blockIdx.x * blockDim.x + threadIdx.x) >> 6);
    const int lane = threadIdx.x & 63;
    int e0 = wave * EDGES_PER_WAVE;
    for (int i = 0; i < EDGES_PER_WAVE; ++i) {
        int e = e0 + i;
        if (e >= n_edges) return;
        int r = rows[e];
        int c = cols[e];
        float v = vals[e];
        float4 hv = reinterpret_cast<const float4*>(h + (size_t)c * F_OUT)[lane];
        float* op = out + (size_t)r * F_OUT + (size_t)lane * 4;
        atomicAdd(op + 0, v * hv.x);
        atomicAdd(op + 1, v * hv.y);
        atomicAdd(op + 2, v * hv.z);
        atomicAdd(op + 3, v * hv.w);
    }
}

// ---------------------------------------------------------------------------
// ReLU in place over out.
// ---------------------------------------------------------------------------
__global__ __launch_bounds__(256) void relu_inplace(float* __restrict__ out, int n4) {
    int i = blockIdx.x * blockDim.x + threadIdx.x;
    if (i < n4) {
        float4 v = reinterpret_cast<float4*>(out)[i];
        v.x = fmaxf(v.x, 0.f);
        v.y = fmaxf(v.y, 0.f);
        v.z = fmaxf(v.z, 0.f);
        v.w = fmaxf(v.w, 0.f);
        reinterpret_cast<float4*>(out)[i] = v;
    }
}

extern "C" void kernel_launch(void* const* d_in, const int* in_sizes, int n_in,
                              void* d_out, int out_size, void* d_ws, size_t ws_size,
                              hipStream_t stream) {
    const float* x    = (const float*)d_in[0];
    const int*   rows = (const int*)d_in[1];
    const int*   cols = (const int*)d_in[2];
    const float* vals = (const float*)d_in[3];
    const float* w    = (const float*)d_in[4];
    float* out = (float*)d_out;

    const int n_nodes = in_sizes[0] / F_IN;
    const int n_edges = in_sizes[1];

    float* h = (float*)d_ws;  // n_nodes * F_OUT fp32 = 102.4 MB scratch

    // Zero the (poisoned) output — scatter accumulates into it.
    hipMemsetAsync(d_out, 0, (size_t)n_nodes * F_OUT * sizeof(float), stream);

    // 1) h = x @ W
    gemm_xw<<<(n_nodes + 31) / 32, 256, 0, stream>>>(x, w, h, n_nodes);

    // 2) scatter-accumulate messages
    int n_waves = (n_edges + EDGES_PER_WAVE - 1) / EDGES_PER_WAVE;
    int blocks = (n_waves + 3) / 4;  // 4 waves per 256-thread block
    spmm_scatter<<<blocks, 256, 0, stream>>>(rows, cols, vals, h, out, n_edges);

    // 3) ReLU
    int n4 = n_nodes * F_OUT / 4;
    relu_inplace<<<(n4 + 255) / 256, 256, 0, stream>>>(out, n4);
}

// Round 2
// 1432.170 us; speedup vs baseline: 7.8249x; 7.8249x over previous
//
#include <hip/hip_runtime.h>

#define F_IN 512
#define F_OUT 256

// ---------------------------------------------------------------------------
// GEMM: h[n, 256] = x[n, 512] @ w[512, 256]   (fp32, vector ALU)
// ---------------------------------------------------------------------------
__global__ __launch_bounds__(256) void gemm_xw(const float* __restrict__ x,
                                               const float* __restrict__ w,
                                               float* __restrict__ h,
                                               int n_nodes) {
    __shared__ float xs[32 * F_IN];  // 64 KiB
    const int row0 = blockIdx.x * 32;
    const int t = threadIdx.x;
    const int rows_here = min(32, n_nodes - row0);

    const float4* xg = reinterpret_cast<const float4*>(x + (size_t)row0 * F_IN);
    float4* xs4 = reinterpret_cast<float4*>(xs);
    if (rows_here == 32) {
#pragma unroll
        for (int i = 0; i < 16; ++i) {
            int idx = i * 256 + t;
            xs4[idx] = xg[idx];
        }
    } else {
        for (int i = 0; i < 16; ++i) {
            int idx = i * 256 + t;
            int r = idx >> 7;
            if (r < rows_here) xs4[idx] = xg[idx];
        }
    }
    __syncthreads();

    const int c = t;
    float acc[32];
#pragma unroll
    for (int r = 0; r < 32; ++r) acc[r] = 0.f;

    for (int k = 0; k < F_IN; k += 4) {
        float wk0 = w[(size_t)(k + 0) * F_OUT + c];
        float wk1 = w[(size_t)(k + 1) * F_OUT + c];
        float wk2 = w[(size_t)(k + 2) * F_OUT + c];
        float wk3 = w[(size_t)(k + 3) * F_OUT + c];
#pragma unroll
        for (int r = 0; r < 32; ++r) {
            float4 xv = *reinterpret_cast<const float4*>(&xs[r * F_IN + k]);
            acc[r] = fmaf(xv.x, wk0, acc[r]);
            acc[r] = fmaf(xv.y, wk1, acc[r]);
            acc[r] = fmaf(xv.z, wk2, acc[r]);
            acc[r] = fmaf(xv.w, wk3, acc[r]);
        }
    }

#pragma unroll
    for (int r = 0; r < 32; ++r) {
        if (r < rows_here) h[(size_t)(row0 + r) * F_OUT + c] = acc[r];
    }
}

// ---------------------------------------------------------------------------
// CSR build step 1: histogram of row degrees. counts must be pre-zeroed.
// ---------------------------------------------------------------------------
__global__ __launch_bounds__(256) void row_histogram(const int* __restrict__ rows,
                                                     int* __restrict__ counts,
                                                     int n_edges) {
    int e = blockIdx.x * blockDim.x + threadIdx.x;
    if (e < n_edges) atomicAdd(&counts[rows[e]], 1);
}

// ---------------------------------------------------------------------------
// CSR build step 2: exclusive prefix scan of counts -> offs (single block,
// 1024 threads, wave-shuffle scan; offs[n] = total).
// ---------------------------------------------------------------------------
__global__ __launch_bounds__(1024) void scan_exclusive(const int* __restrict__ cnt,
                                                       int* __restrict__ offs, int n) {
    __shared__ int wsum[16];
    __shared__ int carry_s;
    const int t = threadIdx.x;
    const int lane = t & 63;
    const int wid = t >> 6;
    if (t == 0) carry_s = 0;
    __syncthreads();

    for (int base = 0; base < n; base += 1024) {
        int i = base + t;
        int v = (i < n) ? cnt[i] : 0;
        // inclusive scan within wave
        int x = v;
#pragma unroll
        for (int d = 1; d < 64; d <<= 1) {
            int y = __shfl_up(x, d, 64);
            if (lane >= d) x += y;
        }
        if (lane == 63) wsum[wid] = x;
        __syncthreads();
        // wave 0 scans the 16 wave totals
        if (wid == 0) {
            int s = (lane < 16) ? wsum[lane] : 0;
#pragma unroll
            for (int d = 1; d < 16; d <<= 1) {
                int y = __shfl_up(s, d, 64);
                if (lane >= d) s += y;
            }
            if (lane < 16) wsum[lane] = s;
        }
        __syncthreads();
        int wave_base = (wid > 0) ? wsum[wid - 1] : 0;
        int carry = carry_s;
        if (i < n) offs[i] = carry + wave_base + (x - v);  // exclusive
        __syncthreads();
        if (t == 0) carry_s = carry + wsum[15];
        __syncthreads();
    }
    if (t == 0) offs[n] = carry_s;
}

// ---------------------------------------------------------------------------
// CSR build step 3: place (col, val) into row-sorted arrays. cursor pre-zeroed.
// (Order within a row is atomic-race-dependent; fp32 sum-order jitter is far
//  below the validation threshold.)
// ---------------------------------------------------------------------------
__global__ __launch_bounds__(256) void place_edges(const int* __restrict__ rows,
                                                   const int* __restrict__ cols,
                                                   const float* __restrict__ vals,
                                                   const int* __restrict__ offs,
                                                   int* __restrict__ cursor,
                                                   int* __restrict__ ecol,
                                                   float* __restrict__ eval,
                                                   int n_edges) {
    int e = blockIdx.x * blockDim.x + threadIdx.x;
    if (e >= n_edges) return;
    int r = rows[e];
    int p = offs[r] + atomicAdd(&cursor[r], 1);
    ecol[p] = cols[e];
    eval[p] = vals[e];
}

// ---------------------------------------------------------------------------
// Segmented SpMM + ReLU: one wave per row. Lane l owns features [4l, 4l+4).
// out[row] = relu( sum_{i in row} eval[i] * h[ecol[i]] )
// ---------------------------------------------------------------------------
__global__ __launch_bounds__(256) void spmm_csr(const int* __restrict__ offs,
                                                const int* __restrict__ ecol,
                                                const float* __restrict__ eval,
                                                const float* __restrict__ h,
                                                float* __restrict__ out,
                                                int n_nodes) {
    const int row = blockIdx.x * 4 + (threadIdx.x >> 6);
    if (row >= n_nodes) return;
    const int lane = threadIdx.x & 63;
    const int beg = offs[row];
    const int end = offs[row + 1];

    float4 acc = make_float4(0.f, 0.f, 0.f, 0.f);
    for (int i = beg; i < end; ++i) {
        int c = ecol[i];       // lane-uniform -> broadcast load
        float v = eval[i];
        float4 hv = reinterpret_cast<const float4*>(h + (size_t)c * F_OUT)[lane];
        acc.x = fmaf(v, hv.x, acc.x);
        acc.y = fmaf(v, hv.y, acc.y);
        acc.z = fmaf(v, hv.z, acc.z);
        acc.w = fmaf(v, hv.w, acc.w);
    }
    acc.x = fmaxf(acc.x, 0.f);
    acc.y = fmaxf(acc.y, 0.f);
    acc.z = fmaxf(acc.z, 0.f);
    acc.w = fmaxf(acc.w, 0.f);
    reinterpret_cast<float4*>(out + (size_t)row * F_OUT)[lane] = acc;
}

// ---------------------------------------------------------------------------
// Fallback (ws too small): atomic scatter + relu, as in round 1.
// ---------------------------------------------------------------------------
__global__ __launch_bounds__(256) void spmm_scatter(const int* __restrict__ rows,
                                                    const int* __restrict__ cols,
                                                    const float* __restrict__ vals,
                                                    const float* __restrict__ h,
                                                    float* __restrict__ out,
                                                    int n_edges) {
    const int wave = (int)((blockIdx.x * blockDim.x + threadIdx.x) >> 6);
    const int lane = threadIdx.x & 63;
    int e0 = wave * 32;
    for (int i = 0; i < 32; ++i) {
        int e = e0 + i;
        if (e >= n_edges) return;
        int r = rows[e];
        int c = cols[e];
        float v = vals[e];
        float4 hv = reinterpret_cast<const float4*>(h + (size_t)c * F_OUT)[lane];
        float* op = out + (size_t)r * F_OUT + (size_t)lane * 4;
        atomicAdd(op + 0, v * hv.x);
        atomicAdd(op + 1, v * hv.y);
        atomicAdd(op + 2, v * hv.z);
        atomicAdd(op + 3, v * hv.w);
    }
}

__global__ __launch_bounds__(256) void relu_inplace(float* __restrict__ out, int n4) {
    int i = blockIdx.x * blockDim.x + threadIdx.x;
    if (i < n4) {
        float4 v = reinterpret_cast<float4*>(out)[i];
        v.x = fmaxf(v.x, 0.f);
        v.y = fmaxf(v.y, 0.f);
        v.z = fmaxf(v.z, 0.f);
        v.w = fmaxf(v.w, 0.f);
        reinterpret_cast<float4*>(out)[i] = v;
    }
}

static inline size_t align_up(size_t v, size_t a) { return (v + a - 1) & ~(a - 1); }

extern "C" void kernel_launch(void* const* d_in, const int* in_sizes, int n_in,
                              void* d_out, int out_size, void* d_ws, size_t ws_size,
                              hipStream_t stream) {
    const float* x    = (const float*)d_in[0];
    const int*   rows = (const int*)d_in[1];
    const int*   cols = (const int*)d_in[2];
    const float* vals = (const float*)d_in[3];
    const float* w    = (const float*)d_in[4];
    float* out = (float*)d_out;

    const int n_nodes = in_sizes[0] / F_IN;
    const int n_edges = in_sizes[1];

    // ---- workspace layout ----
    char* ws = (char*)d_ws;
    size_t off = 0;
    float* h = (float*)(ws + off);            off = align_up(off + (size_t)n_nodes * F_OUT * 4, 256);
    int* ecol = (int*)(ws + off);             off = align_up(off + (size_t)n_edges * 4, 256);
    float* eval = (float*)(ws + off);         off = align_up(off + (size_t)n_edges * 4, 256);
    int* counts = (int*)(ws + off);           off = align_up(off + (size_t)n_nodes * 4, 256);
    int* offs = (int*)(ws + off);             off = align_up(off + ((size_t)n_nodes + 1) * 4, 256);
    int* cursor = (int*)(ws + off);           off = align_up(off + (size_t)n_nodes * 4, 256);
    const bool csr_ok = (off <= ws_size);

    // 1) h = x @ W
    gemm_xw<<<(n_nodes + 31) / 32, 256, 0, stream>>>(x, w, h, n_nodes);

    if (csr_ok) {
        // 2) build CSR
        hipMemsetAsync(counts, 0, (size_t)n_nodes * 4, stream);
        hipMemsetAsync(cursor, 0, (size_t)n_nodes * 4, stream);
        row_histogram<<<(n_edges + 255) / 256, 256, 0, stream>>>(rows, counts, n_edges);
        scan_exclusive<<<1, 1024, 0, stream>>>(counts, offs, n_nodes);
        place_edges<<<(n_edges + 255) / 256, 256, 0, stream>>>(rows, cols, vals, offs,
                                                               cursor, ecol, eval, n_edges);
        // 3) segmented SpMM + ReLU (every row written; no memset of out needed)
        spmm_csr<<<(n_nodes + 3) / 4, 256, 0, stream>>>(offs, ecol, eval, h, out, n_nodes);
    } else {
        hipMemsetAsync(d_out, 0, (size_t)n_nodes * F_OUT * sizeof(float), stream);
        int n_waves = (n_edges + 31) / 32;
        spmm_scatter<<<(n_waves + 3) / 4, 256, 0, stream>>>(rows, cols, vals, h, out, n_edges);
        int n4 = n_nodes * F_OUT / 4;
        relu_inplace<<<(n4 + 255) / 256, 256, 0, stream>>>(out, n4);
    }
}

// Round 3
// 840.423 us; speedup vs baseline: 13.3344x; 1.7041x over previous
//
#include <hip/hip_runtime.h>

#define F_IN 512
#define F_OUT 256
#define BM 64
#define BK 64

typedef __attribute__((ext_vector_type(8))) short bf16x8;
typedef __attribute__((ext_vector_type(4))) float f32x4;

__device__ __forceinline__ ushort f2bf(float f) {
    union { float f; unsigned u; } c{f};
    unsigned r = (c.u + 0x7FFF + ((c.u >> 16) & 1)) >> 16;  // RNE
    return (ushort)r;
}
__device__ __forceinline__ float bf2f(ushort b) {
    union { unsigned u; float f; } c{(unsigned)b << 16};
    return c.f;
}

// ---------------------------------------------------------------------------
// W [512,256] fp32  ->  Wt [256,512] bf16 (transposed). 131072 elems.
// ---------------------------------------------------------------------------
__global__ __launch_bounds__(256) void conv_w(const float* __restrict__ w,
                                              ushort* __restrict__ wt) {
    int idx = blockIdx.x * 256 + threadIdx.x;
    int k = idx & (F_IN - 1);
    int n = idx >> 9;
    wt[(size_t)n * F_IN + k] = f2bf(w[(size_t)k * F_OUT + n]);
}

// ---------------------------------------------------------------------------
// h[M,256](bf16) = x[M,512](fp32 -> bf16) @ Wt^T  via mfma_f32_16x16x32_bf16.
// Block: 256 thr = 4 waves. Tile BM=64 x BN=256; wave w owns cols [64w,64w+64).
// LDS: As[64][64] bf16 (8KB), Bs[256][64] bf16 n-major (32KB), XOR-swizzled:
//   elem(row,k) = row*64 + (k ^ ((row&7)<<3))   (k multiple of 8 per 16B op)
// Fragment maps (16x16x32): A: lane l -> A[l&15][8*(l>>4)+j]
//                           B: lane l -> B[8*(l>>4)+j][l&15]
//                           D: lane l, reg r -> D[4*(l>>4)+r][l&15]
// ---------------------------------------------------------------------------
__global__ __launch_bounds__(256) void gemm_mfma(const float* __restrict__ x,
                                                 const ushort* __restrict__ wt,
                                                 ushort* __restrict__ h,
                                                 int n_nodes) {
    __shared__ short As[BM * BK];      // 8 KB
    __shared__ short Bs[F_OUT * BK];   // 32 KB
    const int t = threadIdx.x;
    const int lane = t & 63;
    const int w = t >> 6;
    const int row0 = blockIdx.x * BM;

    f32x4 acc[4][4] = {};

    // A staging assignment: 4 threads per row, 16 floats each.
    const int arow = t >> 2;
    const int akq = (t & 3) << 4;                  // float offset 0/16/32/48
    const bool avalid = (row0 + arow) < n_nodes;
    const float* xsrc = x + (size_t)(row0 + arow) * F_IN + akq;

    // B staging assignment: 8 lanes per n-row, one 16B chunk each, 8 passes.
    const int bj = t & 7;
    const int brow_base = t >> 3;                  // 0..31

    const int lrow = lane & 15;
    const int koff = (lane >> 4) << 3;             // 0,8,16,24 (elems)

    for (int k0 = 0; k0 < F_IN; k0 += BK) {
        // ---- stage A (fp32 -> bf16) ----
        {
            float4 f[4];
            if (avalid) {
                const float4* s4 = reinterpret_cast<const float4*>(xsrc + k0);
                f[0] = s4[0]; f[1] = s4[1]; f[2] = s4[2]; f[3] = s4[3];
            } else {
                f[0] = f[1] = f[2] = f[3] = make_float4(0.f, 0.f, 0.f, 0.f);
            }
#pragma unroll
            for (int q = 0; q < 2; ++q) {
                bf16x8 v;
                const float* ff = reinterpret_cast<const float*>(&f[q * 2]);
#pragma unroll
                for (int j = 0; j < 8; ++j) v[j] = (short)f2bf(ff[j]);
                int kk = akq + q * 8;
                int idx = arow * BK + (kk ^ ((arow & 7) << 3));
                *reinterpret_cast<bf16x8*>(&As[idx]) = v;
            }
        }
        // ---- stage B (bf16 copy, conflict-free: (row,granule) all distinct) ----
#pragma unroll
        for (int p = 0; p < 8; ++p) {
            int n = p * 32 + brow_base;
            bf16x8 v = *reinterpret_cast<const bf16x8*>(wt + (size_t)n * F_IN + k0 + bj * 8);
            int idx = n * BK + ((bj * 8) ^ ((n & 7) << 3));
            *reinterpret_cast<bf16x8*>(&Bs[idx]) = v;
        }
        __syncthreads();

        // ---- compute ----
#pragma unroll
        for (int kk = 0; kk < BK; kk += 32) {
            bf16x8 a[4], b[4];
#pragma unroll
            for (int m = 0; m < 4; ++m) {
                int r = m * 16 + lrow;
                int idx = r * BK + ((kk + koff) ^ ((r & 7) << 3));
                a[m] = *reinterpret_cast<const bf16x8*>(&As[idx]);
            }
#pragma unroll
            for (int n = 0; n < 4; ++n) {
                int r = w * 64 + n * 16 + lrow;
                int idx = r * BK + ((kk + koff) ^ ((r & 7) << 3));
                b[n] = *reinterpret_cast<const bf16x8*>(&Bs[idx]);
            }
#pragma unroll
            for (int m = 0; m < 4; ++m)
#pragma unroll
                for (int n = 0; n < 4; ++n)
                    acc[m][n] = __builtin_amdgcn_mfma_f32_16x16x32_bf16(a[m], b[n], acc[m][n], 0, 0, 0);
        }
        __syncthreads();
    }

    // ---- epilogue: fp32 acc -> bf16 h ----
    const int rbase = (lane >> 4) << 2;
#pragma unroll
    for (int m = 0; m < 4; ++m) {
#pragma unroll
        for (int r = 0; r < 4; ++r) {
            int orow = row0 + m * 16 + rbase + r;
            if (orow < n_nodes) {
                ushort* dst = h + (size_t)orow * F_OUT + w * 64 + lrow;
#pragma unroll
                for (int n = 0; n < 4; ++n) dst[n * 16] = f2bf(acc[m][n][r]);
            }
        }
    }
}

// ---------------------------------------------------------------------------
// CSR build
// ---------------------------------------------------------------------------
__global__ __launch_bounds__(256) void row_histogram(const int* __restrict__ rows,
                                                     int* __restrict__ counts,
                                                     int n_edges) {
    int e = blockIdx.x * blockDim.x + threadIdx.x;
    if (e < n_edges) atomicAdd(&counts[rows[e]], 1);
}

__global__ __launch_bounds__(1024) void scan_exclusive(const int* __restrict__ cnt,
                                                       int* __restrict__ offs, int n) {
    __shared__ int wsum[16];
    __shared__ int carry_s;
    const int t = threadIdx.x;
    const int lane = t & 63;
    const int wid = t >> 6;
    if (t == 0) carry_s = 0;
    __syncthreads();

    for (int base = 0; base < n; base += 1024) {
        int i = base + t;
        int v = (i < n) ? cnt[i] : 0;
        int x = v;
#pragma unroll
        for (int d = 1; d < 64; d <<= 1) {
            int y = __shfl_up(x, d, 64);
            if (lane >= d) x += y;
        }
        if (lane == 63) wsum[wid] = x;
        __syncthreads();
        if (wid == 0) {
            int s = (lane < 16) ? wsum[lane] : 0;
#pragma unroll
            for (int d = 1; d < 16; d <<= 1) {
                int y = __shfl_up(s, d, 64);
                if (lane >= d) s += y;
            }
            if (lane < 16) wsum[lane] = s;
        }
        __syncthreads();
        int wave_base = (wid > 0) ? wsum[wid - 1] : 0;
        int carry = carry_s;
        if (i < n) offs[i] = carry + wave_base + (x - v);
        __syncthreads();
        if (t == 0) carry_s = carry + wsum[15];
        __syncthreads();
    }
    if (t == 0) offs[n] = carry_s;
}

__global__ __launch_bounds__(256) void place_edges(const int* __restrict__ rows,
                                                   const int* __restrict__ cols,
                                                   const float* __restrict__ vals,
                                                   const int* __restrict__ offs,
                                                   int* __restrict__ cursor,
                                                   int* __restrict__ ecol,
                                                   float* __restrict__ eval,
                                                   int n_edges) {
    int e = blockIdx.x * blockDim.x + threadIdx.x;
    if (e >= n_edges) return;
    int r = rows[e];
    int p = offs[r] + atomicAdd(&cursor[r], 1);
    ecol[p] = cols[e];
    eval[p] = vals[e];
}

// ---------------------------------------------------------------------------
// Segmented SpMM + ReLU: one wave per row; lane owns 4 features (8B bf16 gather).
// ---------------------------------------------------------------------------
__global__ __launch_bounds__(256) void spmm_csr(const int* __restrict__ offs,
                                                const int* __restrict__ ecol,
                                                const float* __restrict__ eval,
                                                const ushort* __restrict__ h,
                                                float* __restrict__ out,
                                                int n_nodes) {
    const int row = blockIdx.x * 4 + (threadIdx.x >> 6);
    if (row >= n_nodes) return;
    const int lane = threadIdx.x & 63;
    const int beg = offs[row];
    const int end = offs[row + 1];

    float4 acc = make_float4(0.f, 0.f, 0.f, 0.f);
    for (int i = beg; i < end; ++i) {
        int c = ecol[i];
        float v = eval[i];
        ushort4 hv = reinterpret_cast<const ushort4*>(h + (size_t)c * F_OUT)[lane];
        acc.x = fmaf(v, bf2f(hv.x), acc.x);
        acc.y = fmaf(v, bf2f(hv.y), acc.y);
        acc.z = fmaf(v, bf2f(hv.z), acc.z);
        acc.w = fmaf(v, bf2f(hv.w), acc.w);
    }
    acc.x = fmaxf(acc.x, 0.f);
    acc.y = fmaxf(acc.y, 0.f);
    acc.z = fmaxf(acc.z, 0.f);
    acc.w = fmaxf(acc.w, 0.f);
    reinterpret_cast<float4*>(out + (size_t)row * F_OUT)[lane] = acc;
}

static inline size_t align_up(size_t v, size_t a) { return (v + a - 1) & ~(a - 1); }

extern "C" void kernel_launch(void* const* d_in, const int* in_sizes, int n_in,
                              void* d_out, int out_size, void* d_ws, size_t ws_size,
                              hipStream_t stream) {
    const float* x    = (const float*)d_in[0];
    const int*   rows = (const int*)d_in[1];
    const int*   cols = (const int*)d_in[2];
    const float* vals = (const float*)d_in[3];
    const float* w    = (const float*)d_in[4];
    float* out = (float*)d_out;

    const int n_nodes = in_sizes[0] / F_IN;
    const int n_edges = in_sizes[1];

    // ---- workspace layout ----
    char* ws = (char*)d_ws;
    size_t off = 0;
    ushort* h  = (ushort*)(ws + off);  off = align_up(off + (size_t)n_nodes * F_OUT * 2, 256);
    ushort* wt = (ushort*)(ws + off);  off = align_up(off + (size_t)F_OUT * F_IN * 2, 256);
    int* ecol  = (int*)(ws + off);     off = align_up(off + (size_t)n_edges * 4, 256);
    float* eval = (float*)(ws + off);  off = align_up(off + (size_t)n_edges * 4, 256);
    int* counts = (int*)(ws + off);    off = align_up(off + (size_t)n_nodes * 4, 256);
    int* offs   = (int*)(ws + off);    off = align_up(off + ((size_t)n_nodes + 1) * 4, 256);
    int* cursor = (int*)(ws + off);    off = align_up(off + (size_t)n_nodes * 4, 256);
    (void)ws_size;

    // 1) Wt = bf16(W^T)
    conv_w<<<(F_IN * F_OUT) / 256, 256, 0, stream>>>(w, wt);

    // 2) h = bf16(x @ W)  (MFMA)
    gemm_mfma<<<(n_nodes + BM - 1) / BM, 256, 0, stream>>>(x, wt, h, n_nodes);

    // 3) build CSR
    hipMemsetAsync(counts, 0, (size_t)n_nodes * 4, stream);
    hipMemsetAsync(cursor, 0, (size_t)n_nodes * 4, stream);
    row_histogram<<<(n_edges + 255) / 256, 256, 0, stream>>>(rows, counts, n_edges);
    scan_exclusive<<<1, 1024, 0, stream>>>(counts, offs, n_nodes);
    place_edges<<<(n_edges + 255) / 256, 256, 0, stream>>>(rows, cols, vals, offs,
                                                           cursor, ecol, eval, n_edges);

    // 4) segmented SpMM + ReLU (every row written; no memset of out needed)
    spmm_csr<<<(n_nodes + 3) / 4, 256, 0, stream>>>(offs, ecol, eval, h, out, n_nodes);
}

// Round 4
// 766.939 us; speedup vs baseline: 14.6120x; 1.0958x over previous
//
#include <hip/hip_runtime.h>

#define F_IN 512
#define F_OUT 256
#define BM 128
#define BN 256
#define BK 64

typedef __attribute__((ext_vector_type(8))) short bf16x8;
typedef __attribute__((ext_vector_type(8))) unsigned short u16x8;
typedef __attribute__((ext_vector_type(4))) float f32x4;

__device__ __forceinline__ ushort f2bf(float f) {
    union { float f; unsigned u; } c{f};
    unsigned r = (c.u + 0x7FFF + ((c.u >> 16) & 1)) >> 16;  // RNE
    return (ushort)r;
}
__device__ __forceinline__ float bf2f(ushort b) {
    union { unsigned u; float f; } c{(unsigned)b << 16};
    return c.f;
}

// ---------------------------------------------------------------------------
// W [512,256] fp32  ->  Wt [256,512] bf16 (transposed). 131072 elems.
// ---------------------------------------------------------------------------
__global__ __launch_bounds__(256) void conv_w(const float* __restrict__ w,
                                              ushort* __restrict__ wt) {
    int idx = blockIdx.x * 256 + threadIdx.x;
    int k = idx & (F_IN - 1);
    int n = idx >> 9;
    wt[(size_t)n * F_IN + k] = f2bf(w[(size_t)k * F_OUT + n]);
}

// ---------------------------------------------------------------------------
// h[M,256](bf16) = x[M,512](fp32->bf16) @ Wt^T  via mfma_f32_16x16x32_bf16.
// Block: 512 thr = 8 waves (2m x 4n), tile 128x256; wave tile 64x64.
// LDS: As[128][64] bf16 (16KB), Bs[256][64] bf16 (32KB), XOR-swizzled:
//   elem(row,k) = row*64 + (k ^ ((row&7)<<3))  (16B granules; frag reads 2-way = free)
// x loads nontemporal (one-shot stream; keep L3 for h).
// ---------------------------------------------------------------------------
__global__ __launch_bounds__(512) void gemm_mfma(const float* __restrict__ x,
                                                 const ushort* __restrict__ wt,
                                                 ushort* __restrict__ h,
                                                 int n_nodes) {
    __shared__ short As[BM * BK];   // 16 KB
    __shared__ short Bs[BN * BK];   // 32 KB
    const int t = threadIdx.x;
    const int lane = t & 63;
    const int w = t >> 6;           // 0..7
    const int wm = w >> 2;          // 0..1
    const int wn = w & 3;           // 0..3
    const int row0 = blockIdx.x * BM;

    f32x4 acc[4][4] = {};

    // A staging: 4 threads per row, 16 floats each.
    const int arow = t >> 2;                 // 0..127
    const int akq  = (t & 3) << 4;           // 0,16,32,48
    const bool avalid = (row0 + arow) < n_nodes;
    const float* xsrc = x + (size_t)(row0 + arow) * F_IN + akq;

    const int lrow = lane & 15;
    const int koff = (lane >> 4) << 3;       // 0,8,16,24

    for (int k0 = 0; k0 < F_IN; k0 += BK) {
        // ---- stage A (fp32 -> bf16), NT loads ----
        {
            f32x4 f[4];
            if (avalid) {
                const f32x4* s4 = reinterpret_cast<const f32x4*>(xsrc + k0);
                f[0] = __builtin_nontemporal_load(s4 + 0);
                f[1] = __builtin_nontemporal_load(s4 + 1);
                f[2] = __builtin_nontemporal_load(s4 + 2);
                f[3] = __builtin_nontemporal_load(s4 + 3);
            } else {
                f[0] = 0.f; f[1] = 0.f; f[2] = 0.f; f[3] = 0.f;
            }
#pragma unroll
            for (int q = 0; q < 2; ++q) {
                bf16x8 v;
#pragma unroll
                for (int j = 0; j < 8; ++j) v[j] = (short)f2bf(f[q * 2 + (j >> 2)][j & 3]);
                int kk = akq + q * 8;
                int idx = arow * BK + (kk ^ ((arow & 7) << 3));
                *reinterpret_cast<bf16x8*>(&As[idx]) = v;
            }
        }
        // ---- stage B (bf16 copy): 2048 chunks, 4 per thread ----
#pragma unroll
        for (int p = 0; p < 4; ++p) {
            int cid = p * 512 + t;
            int n = cid >> 3;
            int j = cid & 7;
            bf16x8 v = *reinterpret_cast<const bf16x8*>(wt + (size_t)n * F_IN + k0 + j * 8);
            int idx = n * BK + ((j * 8) ^ ((n & 7) << 3));
            *reinterpret_cast<bf16x8*>(&Bs[idx]) = v;
        }
        __syncthreads();

        // ---- compute: 32 MFMA / wave / K-tile ----
#pragma unroll
        for (int kk = 0; kk < BK; kk += 32) {
            bf16x8 a[4], b[4];
#pragma unroll
            for (int m = 0; m < 4; ++m) {
                int r = wm * 64 + m * 16 + lrow;
                int idx = r * BK + ((kk + koff) ^ ((r & 7) << 3));
                a[m] = *reinterpret_cast<const bf16x8*>(&As[idx]);
            }
#pragma unroll
            for (int n = 0; n < 4; ++n) {
                int r = wn * 64 + n * 16 + lrow;
                int idx = r * BK + ((kk + koff) ^ ((r & 7) << 3));
                b[n] = *reinterpret_cast<const bf16x8*>(&Bs[idx]);
            }
#pragma unroll
            for (int m = 0; m < 4; ++m)
#pragma unroll
                for (int n = 0; n < 4; ++n)
                    acc[m][n] = __builtin_amdgcn_mfma_f32_16x16x32_bf16(a[m], b[n], acc[m][n], 0, 0, 0);
        }
        __syncthreads();
    }

    // ---- epilogue: fp32 acc -> bf16 h (cached stores; h wants L3 residency) ----
    const int rbase = (lane >> 4) << 2;
#pragma unroll
    for (int m = 0; m < 4; ++m) {
#pragma unroll
        for (int r = 0; r < 4; ++r) {
            int orow = row0 + wm * 64 + m * 16 + rbase + r;
            if (orow < n_nodes) {
                ushort* dst = h + (size_t)orow * F_OUT + wn * 64 + lrow;
#pragma unroll
                for (int n = 0; n < 4; ++n) dst[n * 16] = f2bf(acc[m][n][r]);
            }
        }
    }
}

// ---------------------------------------------------------------------------
// CSR build
// ---------------------------------------------------------------------------
__global__ __launch_bounds__(256) void row_histogram(const int* __restrict__ rows,
                                                     int* __restrict__ counts,
                                                     int n_edges) {
    int e = blockIdx.x * blockDim.x + threadIdx.x;
    if (e < n_edges) atomicAdd(&counts[__builtin_nontemporal_load(rows + e)], 1);
}

// Parallel 3-phase exclusive scan over counts[n] -> offs[n+1].
// Phase A: per-block (2048 elems) sums.
__global__ __launch_bounds__(256) void scan_a(const int* __restrict__ cnt,
                                              int* __restrict__ bsum, int n) {
    __shared__ int wsum[4];
    const int t = threadIdx.x;
    const int base = blockIdx.x * 2048 + t * 8;
    int s = 0;
#pragma unroll
    for (int j = 0; j < 8; ++j) {
        int i = base + j;
        if (i < n) s += cnt[i];
    }
#pragma unroll
    for (int d = 1; d < 64; d <<= 1) s += __shfl_xor(s, d, 64);
    if ((t & 63) == 0) wsum[t >> 6] = s;
    __syncthreads();
    if (t == 0) bsum[blockIdx.x] = wsum[0] + wsum[1] + wsum[2] + wsum[3];
}

// Phase B: single wave scans nb (<=64) block sums -> exclusive bbase; offs[n]=total.
__global__ __launch_bounds__(64) void scan_b(const int* __restrict__ bsum,
                                             int* __restrict__ bbase,
                                             int* __restrict__ offs, int nb, int n) {
    const int lane = threadIdx.x;
    int v = (lane < nb) ? bsum[lane] : 0;
    int x = v;
#pragma unroll
    for (int d = 1; d < 64; d <<= 1) {
        int y = __shfl_up(x, d, 64);
        if (lane >= d) x += y;
    }
    if (lane < nb) bbase[lane] = x - v;
    if (lane == nb - 1) offs[n] = x;  // total = n_edges
}

// Phase C: per-block exclusive scan + bbase -> offs.
__global__ __launch_bounds__(256) void scan_c(const int* __restrict__ cnt,
                                              const int* __restrict__ bbase,
                                              int* __restrict__ offs, int n) {
    __shared__ int wsum[4];
    __shared__ int wbase[4];
    const int t = threadIdx.x;
    const int lane = t & 63;
    const int wid = t >> 6;
    const int base = blockIdx.x * 2048 + t * 8;
    int c[8];
    int tsum = 0;
#pragma unroll
    for (int j = 0; j < 8; ++j) {
        int i = base + j;
        c[j] = (i < n) ? cnt[i] : 0;
        tsum += c[j];
    }
    int x = tsum;
#pragma unroll
    for (int d = 1; d < 64; d <<= 1) {
        int y = __shfl_up(x, d, 64);
        if (lane >= d) x += y;
    }
    if (lane == 63) wsum[wid] = x;
    __syncthreads();
    if (t == 0) {
        int r = 0;
#pragma unroll
        for (int q = 0; q < 4; ++q) { wbase[q] = r; r += wsum[q]; }
    }
    __syncthreads();
    int run = bbase[blockIdx.x] + wbase[wid] + (x - tsum);
#pragma unroll
    for (int j = 0; j < 8; ++j) {
        int i = base + j;
        if (i < n) offs[i] = run;
        run += c[j];
    }
}

__global__ __launch_bounds__(256) void place_edges(const int* __restrict__ rows,
                                                   const int* __restrict__ cols,
                                                   const float* __restrict__ vals,
                                                   const int* __restrict__ offs,
                                                   int* __restrict__ cursor,
                                                   int* __restrict__ ecol,
                                                   float* __restrict__ eval,
                                                   int n_edges) {
    int e = blockIdx.x * blockDim.x + threadIdx.x;
    if (e >= n_edges) return;
    int r = __builtin_nontemporal_load(rows + e);
    int p = offs[r] + atomicAdd(&cursor[r], 1);
    ecol[p] = __builtin_nontemporal_load(cols + e);
    eval[p] = __builtin_nontemporal_load(vals + e);
}

// ---------------------------------------------------------------------------
// Segmented SpMM + ReLU. One wave handles TWO rows (32 lanes each, 16B/lane
// bf16 gathers). Edge loop unrolled x4 -> 4 independent gathers in flight per
// half-wave. out stores nontemporal (never re-read on device; protect L3).
// ---------------------------------------------------------------------------
__global__ __launch_bounds__(256) void spmm_csr(const int* __restrict__ offs,
                                                const int* __restrict__ ecol,
                                                const float* __restrict__ eval,
                                                const ushort* __restrict__ h,
                                                float* __restrict__ out,
                                                int n_nodes) {
    const int wv = (blockIdx.x * blockDim.x + threadIdx.x) >> 6;
    const int lane = threadIdx.x & 63;
    const int half = lane >> 5;
    const int sub = lane & 31;
    const int row = wv * 2 + half;
    const bool valid = row < n_nodes;

    const int beg = valid ? offs[row] : 0;
    const int end = valid ? offs[row + 1] : 0;

    float acc[8] = {0.f, 0.f, 0.f, 0.f, 0.f, 0.f, 0.f, 0.f};
    const ushort* hf = h + sub * 8;

    for (int i = beg; i < end; i += 4) {
        const int rem = end - i;
        int c[4];
        float v[4];
#pragma unroll
        for (int j = 0; j < 4; ++j) {
            bool p = j < rem;
            c[j] = p ? __builtin_nontemporal_load(ecol + i + j) : 0;
            v[j] = p ? __builtin_nontemporal_load(eval + i + j) : 0.f;
        }
        u16x8 g[4];
#pragma unroll
        for (int j = 0; j < 4; ++j)
            g[j] = *reinterpret_cast<const u16x8*>(hf + (size_t)c[j] * F_OUT);
#pragma unroll
        for (int j = 0; j < 4; ++j)
#pragma unroll
            for (int f = 0; f < 8; ++f)
                acc[f] = fmaf(v[j], bf2f((ushort)g[j][f]), acc[f]);
    }

    if (valid) {
        f32x4 o0, o1;
#pragma unroll
        for (int f = 0; f < 4; ++f) {
            o0[f] = fmaxf(acc[f], 0.f);
            o1[f] = fmaxf(acc[f + 4], 0.f);
        }
        f32x4* dst = reinterpret_cast<f32x4*>(out + (size_t)row * F_OUT + sub * 8);
        __builtin_nontemporal_store(o0, dst);
        __builtin_nontemporal_store(o1, dst + 1);
    }
}

static inline size_t align_up(size_t v, size_t a) { return (v + a - 1) & ~(a - 1); }

extern "C" void kernel_launch(void* const* d_in, const int* in_sizes, int n_in,
                              void* d_out, int out_size, void* d_ws, size_t ws_size,
                              hipStream_t stream) {
    const float* x    = (const float*)d_in[0];
    const int*   rows = (const int*)d_in[1];
    const int*   cols = (const int*)d_in[2];
    const float* vals = (const float*)d_in[3];
    const float* w    = (const float*)d_in[4];
    float* out = (float*)d_out;

    const int n_nodes = in_sizes[0] / F_IN;
    const int n_edges = in_sizes[1];

    // ---- workspace layout ----
    char* ws = (char*)d_ws;
    size_t off = 0;
    ushort* h   = (ushort*)(ws + off); off = align_up(off + (size_t)n_nodes * F_OUT * 2, 256);
    ushort* wt  = (ushort*)(ws + off); off = align_up(off + (size_t)F_OUT * F_IN * 2, 256);
    int* ecol   = (int*)(ws + off);    off = align_up(off + (size_t)n_edges * 4, 256);
    float* eval = (float*)(ws + off);  off = align_up(off + (size_t)n_edges * 4, 256);
    int* counts = (int*)(ws + off);    off = align_up(off + (size_t)n_nodes * 4, 256);
    int* offs   = (int*)(ws + off);    off = align_up(off + ((size_t)n_nodes + 1) * 4, 256);
    int* cursor = (int*)(ws + off);    off = align_up(off + (size_t)n_nodes * 4, 256);
    int* bsum   = (int*)(ws + off);    off = align_up(off + 64 * 4, 256);
    int* bbase  = (int*)(ws + off);    off = align_up(off + 64 * 4, 256);
    (void)ws_size;

    const int nb = (n_nodes + 2047) / 2048;  // 49 (<=64 required)

    // 1) Wt = bf16(W^T)
    conv_w<<<(F_IN * F_OUT) / 256, 256, 0, stream>>>(w, wt);

    // 2) h = bf16(x @ W)  (MFMA, 128x256 tile)
    gemm_mfma<<<(n_nodes + BM - 1) / BM, 512, 0, stream>>>(x, wt, h, n_nodes);

    // 3) build CSR
    hipMemsetAsync(counts, 0, (size_t)n_nodes * 4, stream);
    hipMemsetAsync(cursor, 0, (size_t)n_nodes * 4, stream);
    row_histogram<<<(n_edges + 255) / 256, 256, 0, stream>>>(rows, counts, n_edges);
    scan_a<<<nb, 256, 0, stream>>>(counts, bsum, n_nodes);
    scan_b<<<1, 64, 0, stream>>>(bsum, bbase, offs, nb, n_nodes);
    scan_c<<<nb, 256, 0, stream>>>(counts, bbase, offs, n_nodes);
    place_edges<<<(n_edges + 255) / 256, 256, 0, stream>>>(rows, cols, vals, offs,
                                                           cursor, ecol, eval, n_edges);

    // 4) segmented SpMM + ReLU (2 rows/wave, x4 pipelined gathers)
    int n_waves = (n_nodes + 1) / 2;
    spmm_csr<<<(n_waves + 3) / 4, 256, 0, stream>>>(offs, ecol, eval, h, out, n_nodes);
}

// Round 5
// 696.698 us; speedup vs baseline: 16.0852x; 1.1008x over previous
//
#include <hip/hip_runtime.h>

#define F_IN 512
#define F_OUT 256
#define BM 128
#define BN 256
#define BK 64

typedef __attribute__((ext_vector_type(8))) short bf16x8;
typedef __attribute__((ext_vector_type(8))) unsigned short u16x8;
typedef __attribute__((ext_vector_type(4))) float f32x4;

__device__ __forceinline__ ushort f2bf(float f) {
    union { float f; unsigned u; } c{f};
    unsigned r = (c.u + 0x7FFF + ((c.u >> 16) & 1)) >> 16;  // RNE
    return (ushort)r;
}
__device__ __forceinline__ float bf2f(ushort b) {
    union { unsigned u; float f; } c{(unsigned)b << 16};
    return c.f;
}

// ---------------------------------------------------------------------------
// W [512,256] fp32  ->  Wt [256,512] bf16 (transposed). 131072 elems.
// ---------------------------------------------------------------------------
__global__ __launch_bounds__(256) void conv_w(const float* __restrict__ w,
                                              ushort* __restrict__ wt) {
    int idx = blockIdx.x * 256 + threadIdx.x;
    int k = idx & (F_IN - 1);
    int n = idx >> 9;
    wt[(size_t)n * F_IN + k] = f2bf(w[(size_t)k * F_OUT + n]);
}

// ---------------------------------------------------------------------------
// h[M,256](bf16) = x[M,512](fp32->bf16) @ Wt^T  via mfma_f32_16x16x32_bf16.
// Block: 512 thr = 8 waves (2m x 4n), tile 128x256; wave tile 64x64.
// LDS XOR-swizzled (16B granules; frag reads <=2-way = free).
// ---------------------------------------------------------------------------
__global__ __launch_bounds__(512) void gemm_mfma(const float* __restrict__ x,
                                                 const ushort* __restrict__ wt,
                                                 ushort* __restrict__ h,
                                                 int n_nodes) {
    __shared__ short As[BM * BK];   // 16 KB
    __shared__ short Bs[BN * BK];   // 32 KB
    const int t = threadIdx.x;
    const int lane = t & 63;
    const int w = t >> 6;           // 0..7
    const int wm = w >> 2;          // 0..1
    const int wn = w & 3;           // 0..3
    const int row0 = blockIdx.x * BM;

    f32x4 acc[4][4] = {};

    const int arow = t >> 2;                 // 0..127
    const int akq  = (t & 3) << 4;           // 0,16,32,48
    const bool avalid = (row0 + arow) < n_nodes;
    const float* xsrc = x + (size_t)(row0 + arow) * F_IN + akq;

    const int lrow = lane & 15;
    const int koff = (lane >> 4) << 3;       // 0,8,16,24

    for (int k0 = 0; k0 < F_IN; k0 += BK) {
        // ---- stage A (fp32 -> bf16), NT loads ----
        {
            f32x4 f[4];
            if (avalid) {
                const f32x4* s4 = reinterpret_cast<const f32x4*>(xsrc + k0);
                f[0] = __builtin_nontemporal_load(s4 + 0);
                f[1] = __builtin_nontemporal_load(s4 + 1);
                f[2] = __builtin_nontemporal_load(s4 + 2);
                f[3] = __builtin_nontemporal_load(s4 + 3);
            } else {
                f[0] = 0.f; f[1] = 0.f; f[2] = 0.f; f[3] = 0.f;
            }
#pragma unroll
            for (int q = 0; q < 2; ++q) {
                bf16x8 v;
#pragma unroll
                for (int j = 0; j < 8; ++j) v[j] = (short)f2bf(f[q * 2 + (j >> 2)][j & 3]);
                int kk = akq + q * 8;
                int idx = arow * BK + (kk ^ ((arow & 7) << 3));
                *reinterpret_cast<bf16x8*>(&As[idx]) = v;
            }
        }
        // ---- stage B (bf16 copy): 2048 chunks, 4 per thread ----
#pragma unroll
        for (int p = 0; p < 4; ++p) {
            int cid = p * 512 + t;
            int n = cid >> 3;
            int j = cid & 7;
            bf16x8 v = *reinterpret_cast<const bf16x8*>(wt + (size_t)n * F_IN + k0 + j * 8);
            int idx = n * BK + ((j * 8) ^ ((n & 7) << 3));
            *reinterpret_cast<bf16x8*>(&Bs[idx]) = v;
        }
        __syncthreads();

        // ---- compute: 32 MFMA / wave / K-tile ----
#pragma unroll
        for (int kk = 0; kk < BK; kk += 32) {
            bf16x8 a[4], b[4];
#pragma unroll
            for (int m = 0; m < 4; ++m) {
                int r = wm * 64 + m * 16 + lrow;
                int idx = r * BK + ((kk + koff) ^ ((r & 7) << 3));
                a[m] = *reinterpret_cast<const bf16x8*>(&As[idx]);
            }
#pragma unroll
            for (int n = 0; n < 4; ++n) {
                int r = wn * 64 + n * 16 + lrow;
                int idx = r * BK + ((kk + koff) ^ ((r & 7) << 3));
                b[n] = *reinterpret_cast<const bf16x8*>(&Bs[idx]);
            }
#pragma unroll
            for (int m = 0; m < 4; ++m)
#pragma unroll
                for (int n = 0; n < 4; ++n)
                    acc[m][n] = __builtin_amdgcn_mfma_f32_16x16x32_bf16(a[m], b[n], acc[m][n], 0, 0, 0);
        }
        __syncthreads();
    }

    const int rbase = (lane >> 4) << 2;
#pragma unroll
    for (int m = 0; m < 4; ++m) {
#pragma unroll
        for (int r = 0; r < 4; ++r) {
            int orow = row0 + wm * 64 + m * 16 + rbase + r;
            if (orow < n_nodes) {
                ushort* dst = h + (size_t)orow * F_OUT + wn * 64 + lrow;
#pragma unroll
                for (int n = 0; n < 4; ++n) dst[n * 16] = f2bf(acc[m][n][r]);
            }
        }
    }
}

// ---------------------------------------------------------------------------
// CSR build. Rows padded to multiples of 8 edges (padding slots pre-zeroed).
// ---------------------------------------------------------------------------
__global__ __launch_bounds__(256) void row_histogram(const int* __restrict__ rows,
                                                     int* __restrict__ counts,
                                                     int n_edges) {
    int base = (blockIdx.x * blockDim.x + threadIdx.x) * 4;
    if (base + 3 < n_edges) {
        int4 r = *reinterpret_cast<const int4*>(rows + base);
        atomicAdd(&counts[r.x], 1);
        atomicAdd(&counts[r.y], 1);
        atomicAdd(&counts[r.z], 1);
        atomicAdd(&counts[r.w], 1);
    } else {
        for (int j = 0; j < 4; ++j)
            if (base + j < n_edges) atomicAdd(&counts[rows[base + j]], 1);
    }
}

// Phase A: per-block (2048 elems) sums of PADDED counts.
__global__ __launch_bounds__(256) void scan_a(const int* __restrict__ cnt,
                                              int* __restrict__ bsum, int n) {
    __shared__ int wsum[4];
    const int t = threadIdx.x;
    const int base = blockIdx.x * 2048 + t * 8;
    int s = 0;
#pragma unroll
    for (int j = 0; j < 8; ++j) {
        int i = base + j;
        if (i < n) s += (cnt[i] + 7) & ~7;
    }
#pragma unroll
    for (int d = 1; d < 64; d <<= 1) s += __shfl_xor(s, d, 64);
    if ((t & 63) == 0) wsum[t >> 6] = s;
    __syncthreads();
    if (t == 0) bsum[blockIdx.x] = wsum[0] + wsum[1] + wsum[2] + wsum[3];
}

// Phase B: single wave scans nb (<=64) block sums -> exclusive bbase; offs[n]=total.
__global__ __launch_bounds__(64) void scan_b(const int* __restrict__ bsum,
                                             int* __restrict__ bbase,
                                             int* __restrict__ offs, int nb, int n) {
    const int lane = threadIdx.x;
    int v = (lane < nb) ? bsum[lane] : 0;
    int x = v;
#pragma unroll
    for (int d = 1; d < 64; d <<= 1) {
        int y = __shfl_up(x, d, 64);
        if (lane >= d) x += y;
    }
    if (lane < nb) bbase[lane] = x - v;
    if (lane == nb - 1) offs[n] = x;  // padded total
}

// Phase C: per-block exclusive scan of padded counts + bbase -> offs.
__global__ __launch_bounds__(256) void scan_c(const int* __restrict__ cnt,
                                              const int* __restrict__ bbase,
                                              int* __restrict__ offs, int n) {
    __shared__ int wsum[4];
    __shared__ int wbase[4];
    const int t = threadIdx.x;
    const int lane = t & 63;
    const int wid = t >> 6;
    const int base = blockIdx.x * 2048 + t * 8;
    int c[8];
    int tsum = 0;
#pragma unroll
    for (int j = 0; j < 8; ++j) {
        int i = base + j;
        c[j] = (i < n) ? ((cnt[i] + 7) & ~7) : 0;
        tsum += c[j];
    }
    int x = tsum;
#pragma unroll
    for (int d = 1; d < 64; d <<= 1) {
        int y = __shfl_up(x, d, 64);
        if (lane >= d) x += y;
    }
    if (lane == 63) wsum[wid] = x;
    __syncthreads();
    if (t == 0) {
        int r = 0;
#pragma unroll
        for (int q = 0; q < 4; ++q) { wbase[q] = r; r += wsum[q]; }
    }
    __syncthreads();
    int run = bbase[blockIdx.x] + wbase[wid] + (x - tsum);
#pragma unroll
    for (int j = 0; j < 8; ++j) {
        int i = base + j;
        if (i < n) offs[i] = run;
        run += c[j];
    }
}

// Place edges; consumes counts via atomicSub (reverse fill within row).
__global__ __launch_bounds__(256) void place_edges(const int* __restrict__ rows,
                                                   const int* __restrict__ cols,
                                                   const float* __restrict__ vals,
                                                   const int* __restrict__ offs,
                                                   int* __restrict__ counts,
                                                   int* __restrict__ ecol,
                                                   float* __restrict__ eval,
                                                   int n_edges) {
    int base = (blockIdx.x * blockDim.x + threadIdx.x) * 4;
    if (base >= n_edges) return;
    if (base + 3 < n_edges) {
        int4 r = *reinterpret_cast<const int4*>(rows + base);
        int4 c = *reinterpret_cast<const int4*>(cols + base);
        float4 v = *reinterpret_cast<const float4*>(vals + base);
        int rr[4] = {r.x, r.y, r.z, r.w};
        int cc[4] = {c.x, c.y, c.z, c.w};
        float vv[4] = {v.x, v.y, v.z, v.w};
#pragma unroll
        for (int j = 0; j < 4; ++j) {
            int p = offs[rr[j]] + atomicSub(&counts[rr[j]], 1) - 1;
            ecol[p] = cc[j];
            eval[p] = vv[j];
        }
    } else {
        for (int j = 0; j < 4; ++j) {
            if (base + j >= n_edges) break;
            int r = rows[base + j];
            int p = offs[r] + atomicSub(&counts[r], 1) - 1;
            ecol[p] = cols[base + j];
            eval[p] = vals[base + j];
        }
    }
}

// ---------------------------------------------------------------------------
// Segmented SpMM + ReLU. Wave = 2 rows (32 lanes x 16B each). Edge loop in
// batches of 8 (rows padded to x8; padding c=0,v=0 -> harmless FMAs).
// 8 independent gathers in flight per half-wave.
// ---------------------------------------------------------------------------
__global__ __launch_bounds__(256) void spmm_csr(const int* __restrict__ offs,
                                                const int* __restrict__ ecol,
                                                const float* __restrict__ eval,
                                                const ushort* __restrict__ h,
                                                float* __restrict__ out,
                                                int n_nodes) {
    const int wv = (blockIdx.x * blockDim.x + threadIdx.x) >> 6;
    const int lane = threadIdx.x & 63;
    const int half = lane >> 5;
    const int sub = lane & 31;
    const int row = wv * 2 + half;
    const bool valid = row < n_nodes;

    const int beg = valid ? offs[row] : 0;
    const int end = valid ? offs[row + 1] : 0;

    float acc[8] = {0.f, 0.f, 0.f, 0.f, 0.f, 0.f, 0.f, 0.f};
    const ushort* hf = h + sub * 8;

    for (int i = beg; i < end; i += 8) {
        int4 ca = *reinterpret_cast<const int4*>(ecol + i);
        int4 cb = *reinterpret_cast<const int4*>(ecol + i + 4);
        float4 va = *reinterpret_cast<const float4*>(eval + i);
        float4 vb = *reinterpret_cast<const float4*>(eval + i + 4);
        int c[8] = {ca.x, ca.y, ca.z, ca.w, cb.x, cb.y, cb.z, cb.w};
        float v[8] = {va.x, va.y, va.z, va.w, vb.x, vb.y, vb.z, vb.w};
        u16x8 g[8];
#pragma unroll
        for (int j = 0; j < 8; ++j)
            g[j] = *reinterpret_cast<const u16x8*>(hf + (size_t)c[j] * F_OUT);
#pragma unroll
        for (int j = 0; j < 8; ++j)
#pragma unroll
            for (int f = 0; f < 8; ++f)
                acc[f] = fmaf(v[j], bf2f((ushort)g[j][f]), acc[f]);
    }

    if (valid) {
        f32x4 o0, o1;
#pragma unroll
        for (int f = 0; f < 4; ++f) {
            o0[f] = fmaxf(acc[f], 0.f);
            o1[f] = fmaxf(acc[f + 4], 0.f);
        }
        f32x4* dst = reinterpret_cast<f32x4*>(out + (size_t)row * F_OUT + sub * 8);
        __builtin_nontemporal_store(o0, dst);
        __builtin_nontemporal_store(o1, dst + 1);
    }
}

static inline size_t align_up(size_t v, size_t a) { return (v + a - 1) & ~(a - 1); }

extern "C" void kernel_launch(void* const* d_in, const int* in_sizes, int n_in,
                              void* d_out, int out_size, void* d_ws, size_t ws_size,
                              hipStream_t stream) {
    const float* x    = (const float*)d_in[0];
    const int*   rows = (const int*)d_in[1];
    const int*   cols = (const int*)d_in[2];
    const float* vals = (const float*)d_in[3];
    const float* w    = (const float*)d_in[4];
    float* out = (float*)d_out;

    const int n_nodes = in_sizes[0] / F_IN;
    const int n_edges = in_sizes[1];
    const size_t ecap = (size_t)n_edges + 8 * (size_t)n_nodes;  // padded capacity

    // ---- workspace layout ----
    char* ws = (char*)d_ws;
    size_t off = 0;
    ushort* h   = (ushort*)(ws + off); off = align_up(off + (size_t)n_nodes * F_OUT * 2, 256);
    ushort* wt  = (ushort*)(ws + off); off = align_up(off + (size_t)F_OUT * F_IN * 2, 256);
    size_t ecol_off = off;
    int* ecol   = (int*)(ws + off);    off = align_up(off + ecap * 4, 256);
    float* eval = (float*)(ws + off);  off = align_up(off + ecap * 4, 256);
    size_t edge_span = off - ecol_off;
    int* counts = (int*)(ws + off);    off = align_up(off + (size_t)n_nodes * 4, 256);
    int* offs   = (int*)(ws + off);    off = align_up(off + ((size_t)n_nodes + 1) * 4, 256);
    int* bsum   = (int*)(ws + off);    off = align_up(off + 64 * 4, 256);
    int* bbase  = (int*)(ws + off);    off = align_up(off + 64 * 4, 256);
    (void)ws_size;

    const int nb = (n_nodes + 2047) / 2048;  // <=64 required

    // 1) Wt = bf16(W^T)
    conv_w<<<(F_IN * F_OUT) / 256, 256, 0, stream>>>(w, wt);

    // 2) h = bf16(x @ W)  (MFMA, 128x256 tile)
    gemm_mfma<<<(n_nodes + BM - 1) / BM, 512, 0, stream>>>(x, wt, h, n_nodes);

    // 3) build padded CSR
    hipMemsetAsync(counts, 0, (size_t)n_nodes * 4, stream);
    hipMemsetAsync(ws + ecol_off, 0, edge_span, stream);  // zero ecol+eval (incl. padding)
    row_histogram<<<(n_edges / 4 + 255) / 256, 256, 0, stream>>>(rows, counts, n_edges);
    scan_a<<<nb, 256, 0, stream>>>(counts, bsum, n_nodes);
    scan_b<<<1, 64, 0, stream>>>(bsum, bbase, offs, nb, n_nodes);
    scan_c<<<nb, 256, 0, stream>>>(counts, bbase, offs, n_nodes);
    place_edges<<<(n_edges / 4 + 255) / 256, 256, 0, stream>>>(rows, cols, vals, offs,
                                                               counts, ecol, eval, n_edges);

    // 4) segmented SpMM + ReLU (2 rows/wave, 8-deep gather pipeline)
    int n_waves = (n_nodes + 1) / 2;
    spmm_csr<<<(n_waves + 3) / 4, 256, 0, stream>>>(offs, ecol, eval, h, out, n_nodes);
}

// Round 7
// 609.505 us; speedup vs baseline: 18.3863x; 1.1431x over previous
//
#include <hip/hip_runtime.h>

#define F_IN 512
#define F_OUT 256
#define BM 128
#define BN 256
#define BK 64

#define RB_BITS 7            // 128 rows per bucket
#define RPB 128
#define NBUCK 1024           // allocated buckets (used: ceil(n_nodes/128))
#define CAP 6144             // int2 slots per bucket segment (8-aligned)
#define LDSCAP 5120          // max raw edges per bucket handled in LDS (mean 4096, +16 sigma)
#define CURSTRIDE 32         // ints between bucket cursors (own 128B line each)

typedef __attribute__((ext_vector_type(8))) short bf16x8;
typedef __attribute__((ext_vector_type(8))) unsigned short u16x8;
typedef __attribute__((ext_vector_type(4))) float f32x4;
typedef __attribute__((ext_vector_type(4))) int i32x4;

__device__ __forceinline__ ushort f2bf(float f) {
    union { float f; unsigned u; } c{f};
    unsigned r = (c.u + 0x7FFF + ((c.u >> 16) & 1)) >> 16;  // RNE
    return (ushort)r;
}
__device__ __forceinline__ float bf2f(ushort b) {
    union { unsigned u; float f; } c{(unsigned)b << 16};
    return c.f;
}

// ---------------------------------------------------------------------------
// W [512,256] fp32  ->  Wt [256,512] bf16 (transposed). 131072 elems.
// ---------------------------------------------------------------------------
__global__ __launch_bounds__(256) void conv_w(const float* __restrict__ w,
                                              ushort* __restrict__ wt) {
    int idx = blockIdx.x * 256 + threadIdx.x;
    int k = idx & (F_IN - 1);
    int n = idx >> 9;
    wt[(size_t)n * F_IN + k] = f2bf(w[(size_t)k * F_OUT + n]);
}

// ---------------------------------------------------------------------------
// h[M,256](bf16) = x[M,512](fp32->bf16) @ Wt^T  via mfma_f32_16x16x32_bf16.
// 512 thr = 8 waves (2m x 4n), tile 128x256; wave tile 64x64.
// LDS XOR-swizzled (16B granules; frag reads <=2-way = free).
// ---------------------------------------------------------------------------
__global__ __launch_bounds__(512) void gemm_mfma(const float* __restrict__ x,
                                                 const ushort* __restrict__ wt,
                                                 ushort* __restrict__ h,
                                                 int n_nodes) {
    __shared__ short As[BM * BK];   // 16 KB
    __shared__ short Bs[BN * BK];   // 32 KB
    const int t = threadIdx.x;
    const int lane = t & 63;
    const int w = t >> 6;           // 0..7
    const int wm = w >> 2;          // 0..1
    const int wn = w & 3;           // 0..3
    const int row0 = blockIdx.x * BM;

    f32x4 acc[4][4] = {};

    const int arow = t >> 2;                 // 0..127
    const int akq  = (t & 3) << 4;           // 0,16,32,48
    const bool avalid = (row0 + arow) < n_nodes;
    const float* xsrc = x + (size_t)(row0 + arow) * F_IN + akq;

    const int lrow = lane & 15;
    const int koff = (lane >> 4) << 3;       // 0,8,16,24

    for (int k0 = 0; k0 < F_IN; k0 += BK) {
        // ---- stage A (fp32 -> bf16), NT loads ----
        {
            f32x4 f[4];
            if (avalid) {
                const f32x4* s4 = reinterpret_cast<const f32x4*>(xsrc + k0);
                f[0] = __builtin_nontemporal_load(s4 + 0);
                f[1] = __builtin_nontemporal_load(s4 + 1);
                f[2] = __builtin_nontemporal_load(s4 + 2);
                f[3] = __builtin_nontemporal_load(s4 + 3);
            } else {
                f[0] = 0.f; f[1] = 0.f; f[2] = 0.f; f[3] = 0.f;
            }
#pragma unroll
            for (int q = 0; q < 2; ++q) {
                bf16x8 v;
#pragma unroll
                for (int j = 0; j < 8; ++j) v[j] = (short)f2bf(f[q * 2 + (j >> 2)][j & 3]);
                int kk = akq + q * 8;
                int idx = arow * BK + (kk ^ ((arow & 7) << 3));
                *reinterpret_cast<bf16x8*>(&As[idx]) = v;
            }
        }
        // ---- stage B (bf16 copy): 2048 chunks, 4 per thread ----
#pragma unroll
        for (int p = 0; p < 4; ++p) {
            int cid = p * 512 + t;
            int n = cid >> 3;
            int j = cid & 7;
            bf16x8 v = *reinterpret_cast<const bf16x8*>(wt + (size_t)n * F_IN + k0 + j * 8);
            int idx = n * BK + ((j * 8) ^ ((n & 7) << 3));
            *reinterpret_cast<bf16x8*>(&Bs[idx]) = v;
        }
        __syncthreads();

        // ---- compute: 32 MFMA / wave / K-tile ----
#pragma unroll
        for (int kk = 0; kk < BK; kk += 32) {
            bf16x8 a[4], b[4];
#pragma unroll
            for (int m = 0; m < 4; ++m) {
                int r = wm * 64 + m * 16 + lrow;
                int idx = r * BK + ((kk + koff) ^ ((r & 7) << 3));
                a[m] = *reinterpret_cast<const bf16x8*>(&As[idx]);
            }
#pragma unroll
            for (int n = 0; n < 4; ++n) {
                int r = wn * 64 + n * 16 + lrow;
                int idx = r * BK + ((kk + koff) ^ ((r & 7) << 3));
                b[n] = *reinterpret_cast<const bf16x8*>(&Bs[idx]);
            }
#pragma unroll
            for (int m = 0; m < 4; ++m)
#pragma unroll
                for (int n = 0; n < 4; ++n)
                    acc[m][n] = __builtin_amdgcn_mfma_f32_16x16x32_bf16(a[m], b[n], acc[m][n], 0, 0, 0);
        }
        __syncthreads();
    }

    const int rbase = (lane >> 4) << 2;
#pragma unroll
    for (int m = 0; m < 4; ++m) {
#pragma unroll
        for (int r = 0; r < 4; ++r) {
            int orow = row0 + wm * 64 + m * 16 + rbase + r;
            if (orow < n_nodes) {
                ushort* dst = h + (size_t)orow * F_OUT + wn * 64 + lrow;
#pragma unroll
                for (int n = 0; n < 4; ++n) dst[n * 16] = f2bf(acc[m][n][r]);
            }
        }
    }
}

// ---------------------------------------------------------------------------
// Pass 1: append edges into 128-row bucket segments as interleaved int2
//   { (row&127)<<17 | col , bits(val) }.  Append-only frontiers keep write
//   sectors fully utilized (vs round-5's 11x write amplification).
// ---------------------------------------------------------------------------
__global__ __launch_bounds__(256) void bucket_place(const int* __restrict__ rows,
                                                    const int* __restrict__ cols,
                                                    const float* __restrict__ vals,
                                                    int* __restrict__ bcur,
                                                    int2* __restrict__ edges,
                                                    int n_edges) {
    int base = (blockIdx.x * 256 + threadIdx.x) * 4;
    if (base >= n_edges) return;
    if (base + 3 < n_edges) {
        i32x4 r4 = __builtin_nontemporal_load(reinterpret_cast<const i32x4*>(rows + base));
        i32x4 c4 = __builtin_nontemporal_load(reinterpret_cast<const i32x4*>(cols + base));
        f32x4 v4 = __builtin_nontemporal_load(reinterpret_cast<const f32x4*>(vals + base));
#pragma unroll
        for (int j = 0; j < 4; ++j) {
            int r = r4[j];
            int b = r >> RB_BITS;
            int p = atomicAdd(&bcur[b * CURSTRIDE], 1);
            if (p < CAP)
                edges[(size_t)b * CAP + p] =
                    make_int2(((r & (RPB - 1)) << 17) | c4[j], __float_as_int(v4[j]));
        }
    } else {
        for (int j = 0; j < 4 && base + j < n_edges; ++j) {
            int r = rows[base + j];
            int b = r >> RB_BITS;
            int p = atomicAdd(&bcur[b * CURSTRIDE], 1);
            if (p < CAP)
                edges[(size_t)b * CAP + p] =
                    make_int2(((r & (RPB - 1)) << 17) | cols[base + j],
                              __float_as_int(vals[base + j]));
        }
    }
}

// ---------------------------------------------------------------------------
// Pass 2: one block per bucket. Load raw segment to LDS, 128-bin histogram,
// padded(x8) exclusive scan -> per-row [beg,end) offsets (offs/oend arrays),
// zero the pad slots, scatter unpacked {col,val} back row-sorted.
// Race-free: all raw edges are in LDS before any global write.
// Bucket-tail gap slots are NEVER read (oend bounds each row) — this was the
// round-6 crash (end derived from next bucket's base spanned the raw gap).
// ---------------------------------------------------------------------------
__global__ __launch_bounds__(256) void bucket_sort(const int* __restrict__ bcur,
                                                   int2* __restrict__ edges,
                                                   int* __restrict__ offs,
                                                   int* __restrict__ oend,
                                                   int n_nodes) {
    __shared__ int2 raw[LDSCAP];          // 40 KB
    __shared__ int cnt[RPB];
    __shared__ int lcur[RPB];
    __shared__ int wtot;
    const int b = blockIdx.x;
    const int t = threadIdx.x;
    const size_t base = (size_t)b * CAP;

    int nraw = bcur[b * CURSTRIDE];
    if (nraw > LDSCAP) nraw = LDSCAP;

    if (t < RPB) cnt[t] = 0;
    __syncthreads();

    for (int i = t; i < nraw; i += 256) {
        int2 e = edges[base + i];
        raw[i] = e;
        atomicAdd(&cnt[e.x >> 17], 1);
    }
    __syncthreads();

    // padded exclusive scan over 128 bins; barriers uniform across all 256 thr.
    int c = (t < RPB) ? cnt[t] : 0;
    int padded = (c + 7) & ~7;
    int x = padded;
#pragma unroll
    for (int d = 1; d < 64; d <<= 1) {
        int y = __shfl_up(x, d, 64);
        if ((t & 63) >= d) x += y;
    }
    if (t == 63) wtot = x;                 // wave-0 total (threads 0..63)
    __syncthreads();
    if (t < RPB) {
        int mybase = x - padded + ((t >= 64) ? wtot : 0);
        lcur[t] = mybase;
        int gr = (b << RB_BITS) + t;
        if (gr < n_nodes) {
            offs[gr] = (int)base + mybase;
            oend[gr] = (int)base + mybase + padded;
        }
        // zero pad slots [c, padded)
        for (int j = c; j < padded; ++j)
            edges[base + mybase + j] = make_int2(0, 0);
    }
    __syncthreads();

    // scatter sorted
    for (int i = t; i < nraw; i += 256) {
        int2 e = raw[i];
        int r7 = e.x >> 17;
        int pos = atomicAdd(&lcur[r7], 1);
        edges[base + pos] = make_int2(e.x & 0x1FFFF, e.y);
    }
}

// ---------------------------------------------------------------------------
// Segmented SpMM + ReLU. Wave = 2 rows (32 lanes x 16B gathers each). Edge
// loop in batches of 8 (rows padded to x8; pad entries c=0,v=0 -> harmless).
// Edges are interleaved {col,val}: one int4 = 2 edges.
// ---------------------------------------------------------------------------
__global__ __launch_bounds__(256) void spmm_csr(const int* __restrict__ offs,
                                                const int* __restrict__ oend,
                                                const int2* __restrict__ edges,
                                                const ushort* __restrict__ h,
                                                float* __restrict__ out,
                                                int n_nodes) {
    const int wv = (blockIdx.x * blockDim.x + threadIdx.x) >> 6;
    const int lane = threadIdx.x & 63;
    const int half = lane >> 5;
    const int sub = lane & 31;
    const int row = wv * 2 + half;
    const bool valid = row < n_nodes;

    const int beg = valid ? offs[row] : 0;
    const int end = valid ? oend[row] : 0;

    float acc[8] = {0.f, 0.f, 0.f, 0.f, 0.f, 0.f, 0.f, 0.f};
    const ushort* hf = h + sub * 8;

    for (int i = beg; i < end; i += 8) {
        const i32x4* ep = reinterpret_cast<const i32x4*>(edges + i);
        i32x4 e0 = __builtin_nontemporal_load(ep + 0);
        i32x4 e1 = __builtin_nontemporal_load(ep + 1);
        i32x4 e2 = __builtin_nontemporal_load(ep + 2);
        i32x4 e3 = __builtin_nontemporal_load(ep + 3);
        int c[8] = {e0[0], e0[2], e1[0], e1[2], e2[0], e2[2], e3[0], e3[2]};
        float v[8] = {__int_as_float(e0[1]), __int_as_float(e0[3]),
                      __int_as_float(e1[1]), __int_as_float(e1[3]),
                      __int_as_float(e2[1]), __int_as_float(e2[3]),
                      __int_as_float(e3[1]), __int_as_float(e3[3])};
        u16x8 g[8];
#pragma unroll
        for (int j = 0; j < 8; ++j)
            g[j] = *reinterpret_cast<const u16x8*>(hf + (size_t)c[j] * F_OUT);
#pragma unroll
        for (int j = 0; j < 8; ++j)
#pragma unroll
            for (int f = 0; f < 8; ++f)
                acc[f] = fmaf(v[j], bf2f((ushort)g[j][f]), acc[f]);
    }

    if (valid) {
        f32x4 o0, o1;
#pragma unroll
        for (int f = 0; f < 4; ++f) {
            o0[f] = fmaxf(acc[f], 0.f);
            o1[f] = fmaxf(acc[f + 4], 0.f);
        }
        f32x4* dst = reinterpret_cast<f32x4*>(out + (size_t)row * F_OUT + sub * 8);
        __builtin_nontemporal_store(o0, dst);
        __builtin_nontemporal_store(o1, dst + 1);
    }
}

static inline size_t align_up(size_t v, size_t a) { return (v + a - 1) & ~(a - 1); }

extern "C" void kernel_launch(void* const* d_in, const int* in_sizes, int n_in,
                              void* d_out, int out_size, void* d_ws, size_t ws_size,
                              hipStream_t stream) {
    const float* x    = (const float*)d_in[0];
    const int*   rows = (const int*)d_in[1];
    const int*   cols = (const int*)d_in[2];
    const float* vals = (const float*)d_in[3];
    const float* w    = (const float*)d_in[4];
    float* out = (float*)d_out;

    const int n_nodes = in_sizes[0] / F_IN;
    const int n_edges = in_sizes[1];
    const int nbuck_used = (n_nodes + RPB - 1) >> RB_BITS;

    // ---- workspace layout (~103 MB; ws_size >= 129 MB known-good from r2) ----
    char* ws = (char*)d_ws;
    size_t off = 0;
    ushort* h   = (ushort*)(ws + off); off = align_up(off + (size_t)n_nodes * F_OUT * 2, 256);
    ushort* wt  = (ushort*)(ws + off); off = align_up(off + (size_t)F_OUT * F_IN * 2, 256);
    int2* edges = (int2*)(ws + off);   off = align_up(off + (size_t)NBUCK * CAP * 8, 256);
    int* offs   = (int*)(ws + off);    off = align_up(off + (size_t)n_nodes * 4, 256);
    int* oend   = (int*)(ws + off);    off = align_up(off + (size_t)n_nodes * 4, 256);
    int* bcur   = (int*)(ws + off);    off = align_up(off + (size_t)NBUCK * CURSTRIDE * 4, 256);
    (void)ws_size;

    // 1) Wt = bf16(W^T)
    conv_w<<<(F_IN * F_OUT) / 256, 256, 0, stream>>>(w, wt);

    // 2) h = bf16(x @ W)  (MFMA, 128x256 tile)
    gemm_mfma<<<(n_nodes + BM - 1) / BM, 512, 0, stream>>>(x, wt, h, n_nodes);

    // 3) bucketed CSR build
    hipMemsetAsync(bcur, 0, (size_t)NBUCK * CURSTRIDE * 4, stream);
    bucket_place<<<(n_edges / 4 + 255) / 256, 256, 0, stream>>>(rows, cols, vals, bcur,
                                                                edges, n_edges);
    bucket_sort<<<nbuck_used, 256, 0, stream>>>(bcur, edges, offs, oend, n_nodes);

    // 4) segmented SpMM + ReLU (2 rows/wave, 8-deep gather batches)
    int n_waves = (n_nodes + 1) / 2;
    spmm_csr<<<(n_waves + 3) / 4, 256, 0, stream>>>(offs, oend, edges, h, out, n_nodes);
}

// Round 8
// 550.290 us; speedup vs baseline: 20.3647x; 1.1076x over previous
//
#include <hip/hip_runtime.h>

#define F_IN 512
#define F_OUT 256
#define BM 128
#define BN 256
#define BK 64

#define RB_BITS 7            // 128 rows per bucket
#define RPB 128
#define NBUCK 1024           // allocated buckets (used: ceil(n_nodes/128))
#define CAP 6144             // int2 slots per bucket segment (8-aligned)
#define LDSCAP 5120          // max raw edges per bucket handled in LDS
#define CURSTRIDE 32         // ints between bucket cursors (own 128B line each)

typedef __attribute__((ext_vector_type(8))) short bf16x8;
typedef __attribute__((ext_vector_type(4))) float f32x4;
typedef __attribute__((ext_vector_type(4))) int i32x4;

__device__ __forceinline__ ushort f2bf(float f) {
    union { float f; unsigned u; } c{f};
    unsigned r = (c.u + 0x7FFF + ((c.u >> 16) & 1)) >> 16;  // RNE
    return (ushort)r;
}
__device__ __forceinline__ float bf2f(ushort b) {
    union { unsigned u; float f; } c{(unsigned)b << 16};
    return c.f;
}

// ---------------------------------------------------------------------------
// W [512,256] fp32  ->  Wt [256,512] bf16 (transposed). 131072 elems.
// ---------------------------------------------------------------------------
__global__ __launch_bounds__(256) void conv_w(const float* __restrict__ w,
                                              ushort* __restrict__ wt) {
    int idx = blockIdx.x * 256 + threadIdx.x;
    int k = idx & (F_IN - 1);
    int n = idx >> 9;
    wt[(size_t)n * F_IN + k] = f2bf(w[(size_t)k * F_OUT + n]);
}

// ---------------------------------------------------------------------------
// h[M,256](bf16) = x[M,512](fp32->bf16) @ Wt^T  via mfma_f32_16x16x32_bf16.
// 512 thr = 8 waves (2m x 4n), tile 128x256; wave tile 64x64.
// LDS XOR-swizzled (16B granules; frag reads <=2-way = free).
// Register double-buffer: k0+1's global loads issue before the MFMA phase,
// vmcnt-wait lands at next iteration's LDS-write (load latency hides under
// MFMA instead of draining at the barrier).
// ---------------------------------------------------------------------------
__global__ __launch_bounds__(512) void gemm_mfma(const float* __restrict__ x,
                                                 const ushort* __restrict__ wt,
                                                 ushort* __restrict__ h,
                                                 int n_nodes) {
    __shared__ short As[BM * BK];   // 16 KB
    __shared__ short Bs[BN * BK];   // 32 KB
    const int t = threadIdx.x;
    const int lane = t & 63;
    const int w = t >> 6;           // 0..7
    const int wm = w >> 2;          // 0..1
    const int wn = w & 3;           // 0..3
    const int row0 = blockIdx.x * BM;

    f32x4 acc[4][4] = {};

    const int arow = t >> 2;                 // 0..127
    const int akq  = (t & 3) << 4;           // 0,16,32,48
    const bool avalid = (row0 + arow) < n_nodes;
    const float* xsrc = x + (size_t)(row0 + arow) * F_IN + akq;

    const int lrow = lane & 15;
    const int koff = (lane >> 4) << 3;       // 0,8,16,24

    f32x4 fA[4];
    bf16x8 fB[4];

    // prologue: load k0=0 staging regs
    {
        if (avalid) {
            const f32x4* s4 = reinterpret_cast<const f32x4*>(xsrc);
            fA[0] = __builtin_nontemporal_load(s4 + 0);
            fA[1] = __builtin_nontemporal_load(s4 + 1);
            fA[2] = __builtin_nontemporal_load(s4 + 2);
            fA[3] = __builtin_nontemporal_load(s4 + 3);
        } else {
            fA[0] = 0.f; fA[1] = 0.f; fA[2] = 0.f; fA[3] = 0.f;
        }
#pragma unroll
        for (int p = 0; p < 4; ++p) {
            int cid = p * 512 + t;
            int n = cid >> 3;
            int j = cid & 7;
            fB[p] = *reinterpret_cast<const bf16x8*>(wt + (size_t)n * F_IN + j * 8);
        }
    }

    for (int k0 = 0; k0 < F_IN; k0 += BK) {
        // ---- write staged regs to LDS ----
#pragma unroll
        for (int q = 0; q < 2; ++q) {
            bf16x8 v;
#pragma unroll
            for (int j = 0; j < 8; ++j) v[j] = (short)f2bf(fA[q * 2 + (j >> 2)][j & 3]);
            int kk = akq + q * 8;
            int idx = arow * BK + (kk ^ ((arow & 7) << 3));
            *reinterpret_cast<bf16x8*>(&As[idx]) = v;
        }
#pragma unroll
        for (int p = 0; p < 4; ++p) {
            int cid = p * 512 + t;
            int n = cid >> 3;
            int j = cid & 7;
            int idx = n * BK + ((j * 8) ^ ((n & 7) << 3));
            *reinterpret_cast<bf16x8*>(&Bs[idx]) = fB[p];
        }
        __syncthreads();

        // ---- issue next K-tile's global loads (overlap with MFMA below) ----
        if (k0 + BK < F_IN) {
            if (avalid) {
                const f32x4* s4 = reinterpret_cast<const f32x4*>(xsrc + k0 + BK);
                fA[0] = __builtin_nontemporal_load(s4 + 0);
                fA[1] = __builtin_nontemporal_load(s4 + 1);
                fA[2] = __builtin_nontemporal_load(s4 + 2);
                fA[3] = __builtin_nontemporal_load(s4 + 3);
            }
#pragma unroll
            for (int p = 0; p < 4; ++p) {
                int cid = p * 512 + t;
                int n = cid >> 3;
                int j = cid & 7;
                fB[p] = *reinterpret_cast<const bf16x8*>(wt + (size_t)n * F_IN + k0 + BK + j * 8);
            }
        }

        // ---- compute: 32 MFMA / wave / K-tile ----
#pragma unroll
        for (int kk = 0; kk < BK; kk += 32) {
            bf16x8 a[4], b[4];
#pragma unroll
            for (int m = 0; m < 4; ++m) {
                int r = wm * 64 + m * 16 + lrow;
                int idx = r * BK + ((kk + koff) ^ ((r & 7) << 3));
                a[m] = *reinterpret_cast<const bf16x8*>(&As[idx]);
            }
#pragma unroll
            for (int n = 0; n < 4; ++n) {
                int r = wn * 64 + n * 16 + lrow;
                int idx = r * BK + ((kk + koff) ^ ((r & 7) << 3));
                b[n] = *reinterpret_cast<const bf16x8*>(&Bs[idx]);
            }
#pragma unroll
            for (int m = 0; m < 4; ++m)
#pragma unroll
                for (int n = 0; n < 4; ++n)
                    acc[m][n] = __builtin_amdgcn_mfma_f32_16x16x32_bf16(a[m], b[n], acc[m][n], 0, 0, 0);
        }
        __syncthreads();
    }

    const int rbase = (lane >> 4) << 2;
#pragma unroll
    for (int m = 0; m < 4; ++m) {
#pragma unroll
        for (int r = 0; r < 4; ++r) {
            int orow = row0 + wm * 64 + m * 16 + rbase + r;
            if (orow < n_nodes) {
                ushort* dst = h + (size_t)orow * F_OUT + wn * 64 + lrow;
#pragma unroll
                for (int n = 0; n < 4; ++n) dst[n * 16] = f2bf(acc[m][n][r]);
            }
        }
    }
}

// ---------------------------------------------------------------------------
// Pass 1: append edges into 128-row bucket segments as interleaved int2
//   { (row&127)<<17 | col , bits(val) }.
// ---------------------------------------------------------------------------
__global__ __launch_bounds__(256) void bucket_place(const int* __restrict__ rows,
                                                    const int* __restrict__ cols,
                                                    const float* __restrict__ vals,
                                                    int* __restrict__ bcur,
                                                    int2* __restrict__ edges,
                                                    int n_edges) {
    int base = (blockIdx.x * 256 + threadIdx.x) * 4;
    if (base >= n_edges) return;
    if (base + 3 < n_edges) {
        i32x4 r4 = __builtin_nontemporal_load(reinterpret_cast<const i32x4*>(rows + base));
        i32x4 c4 = __builtin_nontemporal_load(reinterpret_cast<const i32x4*>(cols + base));
        f32x4 v4 = __builtin_nontemporal_load(reinterpret_cast<const f32x4*>(vals + base));
#pragma unroll
        for (int j = 0; j < 4; ++j) {
            int r = r4[j];
            int b = r >> RB_BITS;
            int p = atomicAdd(&bcur[b * CURSTRIDE], 1);
            if (p < CAP)
                edges[(size_t)b * CAP + p] =
                    make_int2(((r & (RPB - 1)) << 17) | c4[j], __float_as_int(v4[j]));
        }
    } else {
        for (int j = 0; j < 4 && base + j < n_edges; ++j) {
            int r = rows[base + j];
            int b = r >> RB_BITS;
            int p = atomicAdd(&bcur[b * CURSTRIDE], 1);
            if (p < CAP)
                edges[(size_t)b * CAP + p] =
                    make_int2(((r & (RPB - 1)) << 17) | cols[base + j],
                              __float_as_int(vals[base + j]));
        }
    }
}

// ---------------------------------------------------------------------------
// Pass 2: one block per bucket. LDS histogram + padded(x8) scan -> per-row
// [beg,end) in offs/oend, zero pad slots, scatter unpacked {col,val} sorted.
// ---------------------------------------------------------------------------
__global__ __launch_bounds__(256) void bucket_sort(const int* __restrict__ bcur,
                                                   int2* __restrict__ edges,
                                                   int* __restrict__ offs,
                                                   int* __restrict__ oend,
                                                   int n_nodes) {
    __shared__ int2 raw[LDSCAP];          // 40 KB
    __shared__ int cnt[RPB];
    __shared__ int lcur[RPB];
    __shared__ int wtot;
    const int b = blockIdx.x;
    const int t = threadIdx.x;
    const size_t base = (size_t)b * CAP;

    int nraw = bcur[b * CURSTRIDE];
    if (nraw > LDSCAP) nraw = LDSCAP;

    if (t < RPB) cnt[t] = 0;
    __syncthreads();

    for (int i = t; i < nraw; i += 256) {
        int2 e = edges[base + i];
        raw[i] = e;
        atomicAdd(&cnt[e.x >> 17], 1);
    }
    __syncthreads();

    int c = (t < RPB) ? cnt[t] : 0;
    int padded = (c + 7) & ~7;
    int x = padded;
#pragma unroll
    for (int d = 1; d < 64; d <<= 1) {
        int y = __shfl_up(x, d, 64);
        if ((t & 63) >= d) x += y;
    }
    if (t == 63) wtot = x;                 // wave-0 total
    __syncthreads();
    if (t < RPB) {
        int mybase = x - padded + ((t >= 64) ? wtot : 0);
        lcur[t] = mybase;
        int gr = (b << RB_BITS) + t;
        if (gr < n_nodes) {
            offs[gr] = (int)base + mybase;
            oend[gr] = (int)base + mybase + padded;
        }
        for (int j = c; j < padded; ++j)
            edges[base + mybase + j] = make_int2(0, 0);
    }
    __syncthreads();

    for (int i = t; i < nraw; i += 256) {
        int2 e = raw[i];
        int r7 = e.x >> 17;
        int pos = atomicAdd(&lcur[r7], 1);
        edges[base + pos] = make_int2(e.x & 0x1FFFF, e.y);
    }
}

// ---------------------------------------------------------------------------
// Segmented SpMM + ReLU, ONE ROW PER WAVE (beg/end wave-uniform -> clean
// two-deep software pipeline, no divergence). Lane owns 4 features (8B
// ushort4 gathers; 64 lanes x 8B = 512B per edge, fully coalesced).
// Batch = 8 edges; batch b+1's gathers issue before batch b's FMAs.
// ---------------------------------------------------------------------------
struct EB { i32x4 e0, e1, e2, e3; };
struct GB { ushort4 g0, g1, g2, g3, g4, g5, g6, g7; };

__device__ __forceinline__ void load_eb(EB& e, const int2* __restrict__ edges, int i) {
    const i32x4* ep = reinterpret_cast<const i32x4*>(edges + i);
    e.e0 = __builtin_nontemporal_load(ep + 0);
    e.e1 = __builtin_nontemporal_load(ep + 1);
    e.e2 = __builtin_nontemporal_load(ep + 2);
    e.e3 = __builtin_nontemporal_load(ep + 3);
}
__device__ __forceinline__ void issue_gb(GB& g, const EB& e, const ushort* __restrict__ hf) {
    g.g0 = *reinterpret_cast<const ushort4*>(hf + (size_t)e.e0[0] * F_OUT);
    g.g1 = *reinterpret_cast<const ushort4*>(hf + (size_t)e.e0[2] * F_OUT);
    g.g2 = *reinterpret_cast<const ushort4*>(hf + (size_t)e.e1[0] * F_OUT);
    g.g3 = *reinterpret_cast<const ushort4*>(hf + (size_t)e.e1[2] * F_OUT);
    g.g4 = *reinterpret_cast<const ushort4*>(hf + (size_t)e.e2[0] * F_OUT);
    g.g5 = *reinterpret_cast<const ushort4*>(hf + (size_t)e.e2[2] * F_OUT);
    g.g6 = *reinterpret_cast<const ushort4*>(hf + (size_t)e.e3[0] * F_OUT);
    g.g7 = *reinterpret_cast<const ushort4*>(hf + (size_t)e.e3[2] * F_OUT);
}
__device__ __forceinline__ void fma1(float* acc, float v, ushort4 g) {
    acc[0] = fmaf(v, bf2f(g.x), acc[0]);
    acc[1] = fmaf(v, bf2f(g.y), acc[1]);
    acc[2] = fmaf(v, bf2f(g.z), acc[2]);
    acc[3] = fmaf(v, bf2f(g.w), acc[3]);
}
__device__ __forceinline__ void fma_gb(float* acc, const EB& e, const GB& g) {
    fma1(acc, __int_as_float(e.e0[1]), g.g0);
    fma1(acc, __int_as_float(e.e0[3]), g.g1);
    fma1(acc, __int_as_float(e.e1[1]), g.g2);
    fma1(acc, __int_as_float(e.e1[3]), g.g3);
    fma1(acc, __int_as_float(e.e2[1]), g.g4);
    fma1(acc, __int_as_float(e.e2[3]), g.g5);
    fma1(acc, __int_as_float(e.e3[1]), g.g6);
    fma1(acc, __int_as_float(e.e3[3]), g.g7);
}

__global__ __launch_bounds__(256) void spmm_csr(const int* __restrict__ offs,
                                                const int* __restrict__ oend,
                                                const int2* __restrict__ edges,
                                                const ushort* __restrict__ h,
                                                float* __restrict__ out,
                                                int n_nodes) {
    const int row = (int)((blockIdx.x * blockDim.x + threadIdx.x) >> 6);
    if (row >= n_nodes) return;
    const int lane = threadIdx.x & 63;
    const int beg = offs[row];          // wave-uniform
    const int end = oend[row];
    const int nb = (end - beg) >> 3;    // whole batches (rows padded to x8)

    float acc[4] = {0.f, 0.f, 0.f, 0.f};
    const ushort* hf = h + lane * 4;

    if (nb > 0) {
        EB ea, eb_;
        GB ga, gb;
        load_eb(ea, edges, beg);
        issue_gb(ga, ea, hf);
        int bi = 1;
        for (; bi + 1 < nb; bi += 2) {
            load_eb(eb_, edges, beg + bi * 8);
            issue_gb(gb, eb_, hf);
            fma_gb(acc, ea, ga);
            load_eb(ea, edges, beg + (bi + 1) * 8);
            issue_gb(ga, ea, hf);
            fma_gb(acc, eb_, gb);
        }
        if (bi < nb) {
            load_eb(eb_, edges, beg + bi * 8);
            issue_gb(gb, eb_, hf);
            fma_gb(acc, ea, ga);
            fma_gb(acc, eb_, gb);
        } else {
            fma_gb(acc, ea, ga);
        }
    }

    f32x4 o;
    o[0] = fmaxf(acc[0], 0.f);
    o[1] = fmaxf(acc[1], 0.f);
    o[2] = fmaxf(acc[2], 0.f);
    o[3] = fmaxf(acc[3], 0.f);
    __builtin_nontemporal_store(o, reinterpret_cast<f32x4*>(out + (size_t)row * F_OUT + lane * 4));
}

static inline size_t align_up(size_t v, size_t a) { return (v + a - 1) & ~(a - 1); }

extern "C" void kernel_launch(void* const* d_in, const int* in_sizes, int n_in,
                              void* d_out, int out_size, void* d_ws, size_t ws_size,
                              hipStream_t stream) {
    const float* x    = (const float*)d_in[0];
    const int*   rows = (const int*)d_in[1];
    const int*   cols = (const int*)d_in[2];
    const float* vals = (const float*)d_in[3];
    const float* w    = (const float*)d_in[4];
    float* out = (float*)d_out;

    const int n_nodes = in_sizes[0] / F_IN;
    const int n_edges = in_sizes[1];
    const int nbuck_used = (n_nodes + RPB - 1) >> RB_BITS;

    // ---- workspace layout (~103 MB) ----
    char* ws = (char*)d_ws;
    size_t off = 0;
    ushort* h   = (ushort*)(ws + off); off = align_up(off + (size_t)n_nodes * F_OUT * 2, 256);
    ushort* wt  = (ushort*)(ws + off); off = align_up(off + (size_t)F_OUT * F_IN * 2, 256);
    int2* edges = (int2*)(ws + off);   off = align_up(off + (size_t)NBUCK * CAP * 8, 256);
    int* offs   = (int*)(ws + off);    off = align_up(off + (size_t)n_nodes * 4, 256);
    int* oend   = (int*)(ws + off);    off = align_up(off + (size_t)n_nodes * 4, 256);
    int* bcur   = (int*)(ws + off);    off = align_up(off + (size_t)NBUCK * CURSTRIDE * 4, 256);
    (void)ws_size;

    // 1) Wt = bf16(W^T)
    conv_w<<<(F_IN * F_OUT) / 256, 256, 0, stream>>>(w, wt);

    // 2) h = bf16(x @ W)  (MFMA, 128x256 tile, reg double-buffer)
    gemm_mfma<<<(n_nodes + BM - 1) / BM, 512, 0, stream>>>(x, wt, h, n_nodes);

    // 3) bucketed CSR build
    hipMemsetAsync(bcur, 0, (size_t)NBUCK * CURSTRIDE * 4, stream);
    bucket_place<<<(n_edges / 4 + 255) / 256, 256, 0, stream>>>(rows, cols, vals, bcur,
                                                                edges, n_edges);
    bucket_sort<<<nbuck_used, 256, 0, stream>>>(bcur, edges, offs, oend, n_nodes);

    // 4) segmented SpMM + ReLU (1 row/wave, 2-deep gather pipeline)
    spmm_csr<<<(n_nodes * 64 + 255) / 256, 256, 0, stream>>>(offs, oend, edges, h, out, n_nodes);
}

// Round 9
// 513.525 us; speedup vs baseline: 21.8227x; 1.0716x over previous
//
#include <hip/hip_runtime.h>

#define F_IN 512
#define F_OUT 256
#define BM 128
#define BN 256
#define BK 64

#define RB_BITS 7            // 128 rows per bucket
#define RPB 128
#define NBUCK 1024           // allocated buckets (used: ceil(n_nodes/128))
#define NSUB 8               // sub-buckets (one per XCD via blockIdx&7)
#define CAP_SUB 1024         // int2 slots per sub-segment (mean 512, +24 sigma)
#define LDSCAP 5120          // max raw edges per bucket handled in LDS
#define CSTR 16              // ints between cursors (own 64B line each)

typedef __attribute__((ext_vector_type(8))) short bf16x8;
typedef __attribute__((ext_vector_type(4))) float f32x4;
typedef __attribute__((ext_vector_type(4))) int i32x4;

__device__ __forceinline__ ushort f2bf(float f) {
    union { float f; unsigned u; } c{f};
    unsigned r = (c.u + 0x7FFF + ((c.u >> 16) & 1)) >> 16;  // RNE
    return (ushort)r;
}
__device__ __forceinline__ float bf2f(ushort b) {
    union { unsigned u; float f; } c{(unsigned)b << 16};
    return c.f;
}

// ---------------------------------------------------------------------------
// W [512,256] fp32  ->  Wt [256,512] bf16 (transposed). 131072 elems.
// ---------------------------------------------------------------------------
__global__ __launch_bounds__(256) void conv_w(const float* __restrict__ w,
                                              ushort* __restrict__ wt) {
    int idx = blockIdx.x * 256 + threadIdx.x;
    int k = idx & (F_IN - 1);
    int n = idx >> 9;
    wt[(size_t)n * F_IN + k] = f2bf(w[(size_t)k * F_OUT + n]);
}

// ---------------------------------------------------------------------------
// h[M,256](bf16) = x[M,512](fp32->bf16) @ Wt^T  via mfma_f32_16x16x32_bf16.
// 512 thr = 8 waves (2m x 4n), tile 128x256; wave tile 64x64.
// LDS XOR-swizzled; register double-buffer on the K loop (loads for k0+1
// issue before the MFMA phase; latency hides under MFMA).
// ---------------------------------------------------------------------------
__global__ __launch_bounds__(512) void gemm_mfma(const float* __restrict__ x,
                                                 const ushort* __restrict__ wt,
                                                 ushort* __restrict__ h,
                                                 int n_nodes) {
    __shared__ short As[BM * BK];   // 16 KB
    __shared__ short Bs[BN * BK];   // 32 KB
    const int t = threadIdx.x;
    const int lane = t & 63;
    const int w = t >> 6;           // 0..7
    const int wm = w >> 2;          // 0..1
    const int wn = w & 3;           // 0..3
    const int row0 = blockIdx.x * BM;

    f32x4 acc[4][4] = {};

    const int arow = t >> 2;                 // 0..127
    const int akq  = (t & 3) << 4;           // 0,16,32,48
    const bool avalid = (row0 + arow) < n_nodes;
    const float* xsrc = x + (size_t)(row0 + arow) * F_IN + akq;

    const int lrow = lane & 15;
    const int koff = (lane >> 4) << 3;       // 0,8,16,24

    f32x4 fA[4];
    bf16x8 fB[4];

    // prologue: load k0=0 staging regs
    {
        if (avalid) {
            const f32x4* s4 = reinterpret_cast<const f32x4*>(xsrc);
            fA[0] = __builtin_nontemporal_load(s4 + 0);
            fA[1] = __builtin_nontemporal_load(s4 + 1);
            fA[2] = __builtin_nontemporal_load(s4 + 2);
            fA[3] = __builtin_nontemporal_load(s4 + 3);
        } else {
            fA[0] = 0.f; fA[1] = 0.f; fA[2] = 0.f; fA[3] = 0.f;
        }
#pragma unroll
        for (int p = 0; p < 4; ++p) {
            int cid = p * 512 + t;
            int n = cid >> 3;
            int j = cid & 7;
            fB[p] = *reinterpret_cast<const bf16x8*>(wt + (size_t)n * F_IN + j * 8);
        }
    }

    for (int k0 = 0; k0 < F_IN; k0 += BK) {
        // ---- write staged regs to LDS ----
#pragma unroll
        for (int q = 0; q < 2; ++q) {
            bf16x8 v;
#pragma unroll
            for (int j = 0; j < 8; ++j) v[j] = (short)f2bf(fA[q * 2 + (j >> 2)][j & 3]);
            int kk = akq + q * 8;
            int idx = arow * BK + (kk ^ ((arow & 7) << 3));
            *reinterpret_cast<bf16x8*>(&As[idx]) = v;
        }
#pragma unroll
        for (int p = 0; p < 4; ++p) {
            int cid = p * 512 + t;
            int n = cid >> 3;
            int j = cid & 7;
            int idx = n * BK + ((j * 8) ^ ((n & 7) << 3));
            *reinterpret_cast<bf16x8*>(&Bs[idx]) = fB[p];
        }
        __syncthreads();

        // ---- issue next K-tile's global loads (overlap with MFMA below) ----
        if (k0 + BK < F_IN) {
            if (avalid) {
                const f32x4* s4 = reinterpret_cast<const f32x4*>(xsrc + k0 + BK);
                fA[0] = __builtin_nontemporal_load(s4 + 0);
                fA[1] = __builtin_nontemporal_load(s4 + 1);
                fA[2] = __builtin_nontemporal_load(s4 + 2);
                fA[3] = __builtin_nontemporal_load(s4 + 3);
            }
#pragma unroll
            for (int p = 0; p < 4; ++p) {
                int cid = p * 512 + t;
                int n = cid >> 3;
                int j = cid & 7;
                fB[p] = *reinterpret_cast<const bf16x8*>(wt + (size_t)n * F_IN + k0 + BK + j * 8);
            }
        }

        // ---- compute: 32 MFMA / wave / K-tile ----
#pragma unroll
        for (int kk = 0; kk < BK; kk += 32) {
            bf16x8 a[4], b[4];
#pragma unroll
            for (int m = 0; m < 4; ++m) {
                int r = wm * 64 + m * 16 + lrow;
                int idx = r * BK + ((kk + koff) ^ ((r & 7) << 3));
                a[m] = *reinterpret_cast<const bf16x8*>(&As[idx]);
            }
#pragma unroll
            for (int n = 0; n < 4; ++n) {
                int r = wn * 64 + n * 16 + lrow;
                int idx = r * BK + ((kk + koff) ^ ((r & 7) << 3));
                b[n] = *reinterpret_cast<const bf16x8*>(&Bs[idx]);
            }
#pragma unroll
            for (int m = 0; m < 4; ++m)
#pragma unroll
                for (int n = 0; n < 4; ++n)
                    acc[m][n] = __builtin_amdgcn_mfma_f32_16x16x32_bf16(a[m], b[n], acc[m][n], 0, 0, 0);
        }
        __syncthreads();
    }

    const int rbase = (lane >> 4) << 2;
#pragma unroll
    for (int m = 0; m < 4; ++m) {
#pragma unroll
        for (int r = 0; r < 4; ++r) {
            int orow = row0 + wm * 64 + m * 16 + rbase + r;
            if (orow < n_nodes) {
                ushort* dst = h + (size_t)orow * F_OUT + wn * 64 + lrow;
#pragma unroll
                for (int n = 0; n < 4; ++n) dst[n * 16] = f2bf(acc[m][n][r]);
            }
        }
    }
}

// ---------------------------------------------------------------------------
// Pass 1: append edges into per-(bucket, blockIdx&7) sub-segments as int2
//   { (row&127)<<17 | col , bits(val) }.
// Sub-split: 8192 cursors (64B apart) cuts same-address atomic contention
// 8x, and aligns append frontiers with XCDs (blockIdx round-robins XCDs) so
// L2 lines are dirtied by one XCD -> full-line writebacks.
// ---------------------------------------------------------------------------
__global__ __launch_bounds__(256) void bucket_place(const int* __restrict__ rows,
                                                    const int* __restrict__ cols,
                                                    const float* __restrict__ vals,
                                                    int* __restrict__ bcur,
                                                    int2* __restrict__ edges,
                                                    int n_edges) {
    const int sub = blockIdx.x & (NSUB - 1);
    int base = (blockIdx.x * 256 + threadIdx.x) * 4;
    if (base >= n_edges) return;
    if (base + 3 < n_edges) {
        i32x4 r4 = __builtin_nontemporal_load(reinterpret_cast<const i32x4*>(rows + base));
        i32x4 c4 = __builtin_nontemporal_load(reinterpret_cast<const i32x4*>(cols + base));
        f32x4 v4 = __builtin_nontemporal_load(reinterpret_cast<const f32x4*>(vals + base));
#pragma unroll
        for (int j = 0; j < 4; ++j) {
            int r = r4[j];
            int bs = (r >> RB_BITS) * NSUB + sub;
            int p = atomicAdd(&bcur[bs * CSTR], 1);
            if (p < CAP_SUB)
                edges[(size_t)bs * CAP_SUB + p] =
                    make_int2(((r & (RPB - 1)) << 17) | c4[j], __float_as_int(v4[j]));
        }
    } else {
        for (int j = 0; j < 4 && base + j < n_edges; ++j) {
            int r = rows[base + j];
            int bs = (r >> RB_BITS) * NSUB + sub;
            int p = atomicAdd(&bcur[bs * CSTR], 1);
            if (p < CAP_SUB)
                edges[(size_t)bs * CAP_SUB + p] =
                    make_int2(((r & (RPB - 1)) << 17) | cols[base + j],
                              __float_as_int(vals[base + j]));
        }
    }
}

// ---------------------------------------------------------------------------
// Pass 2: one block per bucket. Concatenate the 8 sub-lists into LDS with a
// 128-bin histogram, padded(x8) scan -> per-row [beg,end) in offs/oend, zero
// pad slots, scatter unpacked {col,val} row-sorted into the bucket's
// contiguous 8192-slot region. All raw data is in LDS before any write.
// ---------------------------------------------------------------------------
__global__ __launch_bounds__(256) void bucket_sort(const int* __restrict__ bcur,
                                                   int2* __restrict__ edges,
                                                   int* __restrict__ offs,
                                                   int* __restrict__ oend,
                                                   int n_nodes) {
    __shared__ int2 raw[LDSCAP];          // 40 KB
    __shared__ int cnt[RPB];
    __shared__ int lcur[RPB];
    __shared__ int wtot;
    const int b = blockIdx.x;
    const int t = threadIdx.x;
    const size_t bbase = (size_t)b * NSUB * CAP_SUB;

    if (t < RPB) cnt[t] = 0;
    __syncthreads();

    // concatenate sub-lists into LDS + histogram
    int nraw = 0;
#pragma unroll
    for (int s = 0; s < NSUB; ++s) {
        int ns = bcur[(b * NSUB + s) * CSTR];
        if (ns > CAP_SUB) ns = CAP_SUB;
        int take = ns;
        if (nraw + take > LDSCAP) take = LDSCAP - nraw;
        for (int i = t; i < take; i += 256) {
            int2 e = edges[bbase + (size_t)s * CAP_SUB + i];
            raw[nraw + i] = e;
            atomicAdd(&cnt[e.x >> 17], 1);
        }
        nraw += take;
    }
    __syncthreads();

    int c = (t < RPB) ? cnt[t] : 0;
    int padded = (c + 7) & ~7;
    int x = padded;
#pragma unroll
    for (int d = 1; d < 64; d <<= 1) {
        int y = __shfl_up(x, d, 64);
        if ((t & 63) >= d) x += y;
    }
    if (t == 63) wtot = x;                 // wave-0 total
    __syncthreads();
    if (t < RPB) {
        int mybase = x - padded + ((t >= 64) ? wtot : 0);
        lcur[t] = mybase;
        int gr = (b << RB_BITS) + t;
        if (gr < n_nodes) {
            offs[gr] = (int)bbase + mybase;
            oend[gr] = (int)bbase + mybase + padded;
        }
        for (int j = c; j < padded; ++j)
            edges[bbase + mybase + j] = make_int2(0, 0);
    }
    __syncthreads();

    for (int i = t; i < nraw; i += 256) {
        int2 e = raw[i];
        int r7 = e.x >> 17;
        int pos = atomicAdd(&lcur[r7], 1);
        edges[bbase + pos] = make_int2(e.x & 0x1FFFF, e.y);
    }
}

// ---------------------------------------------------------------------------
// Segmented SpMM + ReLU, one row per wave; lane owns 4 features (8B ushort4
// gathers, 512B/edge coalesced). Two-deep software pipeline: batch b+1's 8
// gathers issue before batch b's FMAs.
// ---------------------------------------------------------------------------
struct EB { i32x4 e0, e1, e2, e3; };
struct GB { ushort4 g0, g1, g2, g3, g4, g5, g6, g7; };

__device__ __forceinline__ void load_eb(EB& e, const int2* __restrict__ edges, int i) {
    const i32x4* ep = reinterpret_cast<const i32x4*>(edges + i);
    e.e0 = __builtin_nontemporal_load(ep + 0);
    e.e1 = __builtin_nontemporal_load(ep + 1);
    e.e2 = __builtin_nontemporal_load(ep + 2);
    e.e3 = __builtin_nontemporal_load(ep + 3);
}
__device__ __forceinline__ void issue_gb(GB& g, const EB& e, const ushort* __restrict__ hf) {
    g.g0 = *reinterpret_cast<const ushort4*>(hf + (size_t)e.e0[0] * F_OUT);
    g.g1 = *reinterpret_cast<const ushort4*>(hf + (size_t)e.e0[2] * F_OUT);
    g.g2 = *reinterpret_cast<const ushort4*>(hf + (size_t)e.e1[0] * F_OUT);
    g.g3 = *reinterpret_cast<const ushort4*>(hf + (size_t)e.e1[2] * F_OUT);
    g.g4 = *reinterpret_cast<const ushort4*>(hf + (size_t)e.e2[0] * F_OUT);
    g.g5 = *reinterpret_cast<const ushort4*>(hf + (size_t)e.e2[2] * F_OUT);
    g.g6 = *reinterpret_cast<const ushort4*>(hf + (size_t)e.e3[0] * F_OUT);
    g.g7 = *reinterpret_cast<const ushort4*>(hf + (size_t)e.e3[2] * F_OUT);
}
__device__ __forceinline__ void fma1(float* acc, float v, ushort4 g) {
    acc[0] = fmaf(v, bf2f(g.x), acc[0]);
    acc[1] = fmaf(v, bf2f(g.y), acc[1]);
    acc[2] = fmaf(v, bf2f(g.z), acc[2]);
    acc[3] = fmaf(v, bf2f(g.w), acc[3]);
}
__device__ __forceinline__ void fma_gb(float* acc, const EB& e, const GB& g) {
    fma1(acc, __int_as_float(e.e0[1]), g.g0);
    fma1(acc, __int_as_float(e.e0[3]), g.g1);
    fma1(acc, __int_as_float(e.e1[1]), g.g2);
    fma1(acc, __int_as_float(e.e1[3]), g.g3);
    fma1(acc, __int_as_float(e.e2[1]), g.g4);
    fma1(acc, __int_as_float(e.e2[3]), g.g5);
    fma1(acc, __int_as_float(e.e3[1]), g.g6);
    fma1(acc, __int_as_float(e.e3[3]), g.g7);
}

__global__ __launch_bounds__(256) void spmm_csr(const int* __restrict__ offs,
                                                const int* __restrict__ oend,
                                                const int2* __restrict__ edges,
                                                const ushort* __restrict__ h,
                                                float* __restrict__ out,
                                                int n_nodes) {
    const int row = (int)((blockIdx.x * blockDim.x + threadIdx.x) >> 6);
    if (row >= n_nodes) return;
    const int lane = threadIdx.x & 63;
    const int beg = offs[row];          // wave-uniform
    const int end = oend[row];
    const int nb = (end - beg) >> 3;    // whole batches (rows padded to x8)

    float acc[4] = {0.f, 0.f, 0.f, 0.f};
    const ushort* hf = h + lane * 4;

    if (nb > 0) {
        EB ea, eb_;
        GB ga, gb;
        load_eb(ea, edges, beg);
        issue_gb(ga, ea, hf);
        int bi = 1;
        for (; bi + 1 < nb; bi += 2) {
            load_eb(eb_, edges, beg + bi * 8);
            issue_gb(gb, eb_, hf);
            fma_gb(acc, ea, ga);
            load_eb(ea, edges, beg + (bi + 1) * 8);
            issue_gb(ga, ea, hf);
            fma_gb(acc, eb_, gb);
        }
        if (bi < nb) {
            load_eb(eb_, edges, beg + bi * 8);
            issue_gb(gb, eb_, hf);
            fma_gb(acc, ea, ga);
            fma_gb(acc, eb_, gb);
        } else {
            fma_gb(acc, ea, ga);
        }
    }

    f32x4 o;
    o[0] = fmaxf(acc[0], 0.f);
    o[1] = fmaxf(acc[1], 0.f);
    o[2] = fmaxf(acc[2], 0.f);
    o[3] = fmaxf(acc[3], 0.f);
    __builtin_nontemporal_store(o, reinterpret_cast<f32x4*>(out + (size_t)row * F_OUT + lane * 4));
}

static inline size_t align_up(size_t v, size_t a) { return (v + a - 1) & ~(a - 1); }

extern "C" void kernel_launch(void* const* d_in, const int* in_sizes, int n_in,
                              void* d_out, int out_size, void* d_ws, size_t ws_size,
                              hipStream_t stream) {
    const float* x    = (const float*)d_in[0];
    const int*   rows = (const int*)d_in[1];
    const int*   cols = (const int*)d_in[2];
    const float* vals = (const float*)d_in[3];
    const float* w    = (const float*)d_in[4];
    float* out = (float*)d_out;

    const int n_nodes = in_sizes[0] / F_IN;
    const int n_edges = in_sizes[1];
    const int nbuck_used = (n_nodes + RPB - 1) >> RB_BITS;

    // ---- workspace layout (~120 MB) ----
    char* ws = (char*)d_ws;
    size_t off = 0;
    ushort* h   = (ushort*)(ws + off); off = align_up(off + (size_t)n_nodes * F_OUT * 2, 256);
    ushort* wt  = (ushort*)(ws + off); off = align_up(off + (size_t)F_OUT * F_IN * 2, 256);
    int2* edges = (int2*)(ws + off);   off = align_up(off + (size_t)NBUCK * NSUB * CAP_SUB * 8, 256);
    int* offs   = (int*)(ws + off);    off = align_up(off + (size_t)n_nodes * 4, 256);
    int* oend   = (int*)(ws + off);    off = align_up(off + (size_t)n_nodes * 4, 256);
    int* bcur   = (int*)(ws + off);    off = align_up(off + (size_t)NBUCK * NSUB * CSTR * 4, 256);
    (void)ws_size;

    // 1) Wt = bf16(W^T)
    conv_w<<<(F_IN * F_OUT) / 256, 256, 0, stream>>>(w, wt);

    // 2) h = bf16(x @ W)  (MFMA, 128x256 tile, reg double-buffer)
    gemm_mfma<<<(n_nodes + BM - 1) / BM, 512, 0, stream>>>(x, wt, h, n_nodes);

    // 3) bucketed CSR build (8 XCD-aligned sub-buckets per bucket)
    hipMemsetAsync(bcur, 0, (size_t)NBUCK * NSUB * CSTR * 4, stream);
    bucket_place<<<(n_edges / 4 + 255) / 256, 256, 0, stream>>>(rows, cols, vals, bcur,
                                                                edges, n_edges);
    bucket_sort<<<nbuck_used, 256, 0, stream>>>(bcur, edges, offs, oend, n_nodes);

    // 4) segmented SpMM + ReLU (1 row/wave, 2-deep gather pipeline)
    spmm_csr<<<(n_nodes * 64 + 255) / 256, 256, 0, stream>>>(offs, oend, edges, h, out, n_nodes);
}

// Round 10
// 448.904 us; speedup vs baseline: 24.9642x; 1.1440x over previous
//
#include <hip/hip_runtime.h>

#define F_IN 512
#define F_OUT 256
#define BM 128
#define BN 256
#define BK 64

#define RB_BITS 7            // 128 rows per bucket
#define RPB 128
#define NBUCK 1024           // allocated buckets (used: ceil(n_nodes/128))
#define NSUB 8               // sub-buckets (one per XCD via blockIdx&7)
#define CAP_SUB 1024         // int2 slots per sub-segment (mean 512, +24 sigma)
#define LDSCAP 5120          // max raw edges per bucket handled in LDS
#define CSTR 16              // ints between cursors (own 64B line each)
#define NBIN (RPB * 32)      // 4096 sort bins: (row7<<5) | (col>>12)

typedef __attribute__((ext_vector_type(8))) short bf16x8;
typedef __attribute__((ext_vector_type(4))) float f32x4;
typedef __attribute__((ext_vector_type(4))) int i32x4;

__device__ __forceinline__ ushort f2bf(float f) {
    union { float f; unsigned u; } c{f};
    unsigned r = (c.u + 0x7FFF + ((c.u >> 16) & 1)) >> 16;  // RNE
    return (ushort)r;
}
__device__ __forceinline__ float bf2f(ushort b) {
    union { unsigned u; float f; } c{(unsigned)b << 16};
    return c.f;
}

// ---------------------------------------------------------------------------
// W [512,256] fp32  ->  Wt [256,512] bf16 (transposed). 131072 elems.
// ---------------------------------------------------------------------------
__global__ __launch_bounds__(256) void conv_w(const float* __restrict__ w,
                                              ushort* __restrict__ wt) {
    int idx = blockIdx.x * 256 + threadIdx.x;
    int k = idx & (F_IN - 1);
    int n = idx >> 9;
    wt[(size_t)n * F_IN + k] = f2bf(w[(size_t)k * F_OUT + n]);
}

// ---------------------------------------------------------------------------
// FUSED kernel: gemm blocks + bucket_place blocks interleaved 1:2 by
// blockIdx%3. gemm is MFMA/VALU-bound, place is fabric-latency-bound with
// 0.4% VALU — complementary pipes co-resident on each CU overlap (m114),
// hiding place's ~50us instead of serializing it.
//
// gemm: h[M,256](bf16) = x(fp32->bf16) @ Wt^T, 8 waves, 128x256 tile,
//       XOR-swizzled LDS, register double-buffer on the K loop.
// place: append edges into per-(bucket, bid&7) sub-segments as int2
//       {(row&127)<<17|col, val}; 8192 cursors cut atomic contention and
//       align append frontiers with XCDs (full-line writebacks).
// ---------------------------------------------------------------------------
__global__ __launch_bounds__(512) void gemm_place(const float* __restrict__ x,
                                                  const ushort* __restrict__ wt,
                                                  ushort* __restrict__ h,
                                                  int n_nodes,
                                                  const int* __restrict__ rows,
                                                  const int* __restrict__ cols,
                                                  const float* __restrict__ vals,
                                                  int* __restrict__ bcur,
                                                  int2* __restrict__ edges,
                                                  int n_edges,
                                                  int ngemm) {
    __shared__ short As[BM * BK];   // 16 KB
    __shared__ short Bs[BN * BK];   // 32 KB
    const int bid = blockIdx.x;
    const int t = threadIdx.x;

    const bool is_gemm = (bid % 3 == 0) && (bid / 3 < ngemm);
    if (!is_gemm) {
        // ---------------- bucket_place path ----------------
        const int place_id = (bid < 3 * ngemm) ? (bid - bid / 3 - 1) : (bid - ngemm);
        const int sub = bid & (NSUB - 1);
        int base = (place_id * 512 + t) * 4;
        if (base >= n_edges) return;
        if (base + 3 < n_edges) {
            i32x4 r4 = __builtin_nontemporal_load(reinterpret_cast<const i32x4*>(rows + base));
            i32x4 c4 = __builtin_nontemporal_load(reinterpret_cast<const i32x4*>(cols + base));
            f32x4 v4 = __builtin_nontemporal_load(reinterpret_cast<const f32x4*>(vals + base));
#pragma unroll
            for (int j = 0; j < 4; ++j) {
                int r = r4[j];
                int bs = (r >> RB_BITS) * NSUB + sub;
                int p = atomicAdd(&bcur[bs * CSTR], 1);
                if (p < CAP_SUB)
                    edges[(size_t)bs * CAP_SUB + p] =
                        make_int2(((r & (RPB - 1)) << 17) | c4[j], __float_as_int(v4[j]));
            }
        } else {
            for (int j = 0; j < 4 && base + j < n_edges; ++j) {
                int r = rows[base + j];
                int bs = (r >> RB_BITS) * NSUB + sub;
                int p = atomicAdd(&bcur[bs * CSTR], 1);
                if (p < CAP_SUB)
                    edges[(size_t)bs * CAP_SUB + p] =
                        make_int2(((r & (RPB - 1)) << 17) | cols[base + j],
                                  __float_as_int(vals[base + j]));
            }
        }
        return;
    }

    // ---------------- gemm path ----------------
    const int gb = bid / 3;
    const int lane = t & 63;
    const int w = t >> 6;           // 0..7
    const int wm = w >> 2;          // 0..1
    const int wn = w & 3;           // 0..3
    const int row0 = gb * BM;

    f32x4 acc[4][4] = {};

    const int arow = t >> 2;                 // 0..127
    const int akq  = (t & 3) << 4;           // 0,16,32,48
    const bool avalid = (row0 + arow) < n_nodes;
    const float* xsrc = x + (size_t)(row0 + arow) * F_IN + akq;

    const int lrow = lane & 15;
    const int koff = (lane >> 4) << 3;       // 0,8,16,24

    f32x4 fA[4];
    bf16x8 fB[4];

    // prologue: load k0=0 staging regs
    {
        if (avalid) {
            const f32x4* s4 = reinterpret_cast<const f32x4*>(xsrc);
            fA[0] = __builtin_nontemporal_load(s4 + 0);
            fA[1] = __builtin_nontemporal_load(s4 + 1);
            fA[2] = __builtin_nontemporal_load(s4 + 2);
            fA[3] = __builtin_nontemporal_load(s4 + 3);
        } else {
            fA[0] = 0.f; fA[1] = 0.f; fA[2] = 0.f; fA[3] = 0.f;
        }
#pragma unroll
        for (int p = 0; p < 4; ++p) {
            int cid = p * 512 + t;
            int n = cid >> 3;
            int j = cid & 7;
            fB[p] = *reinterpret_cast<const bf16x8*>(wt + (size_t)n * F_IN + j * 8);
        }
    }

    for (int k0 = 0; k0 < F_IN; k0 += BK) {
        // ---- write staged regs to LDS ----
#pragma unroll
        for (int q = 0; q < 2; ++q) {
            bf16x8 v;
#pragma unroll
            for (int j = 0; j < 8; ++j) v[j] = (short)f2bf(fA[q * 2 + (j >> 2)][j & 3]);
            int kk = akq + q * 8;
            int idx = arow * BK + (kk ^ ((arow & 7) << 3));
            *reinterpret_cast<bf16x8*>(&As[idx]) = v;
        }
#pragma unroll
        for (int p = 0; p < 4; ++p) {
            int cid = p * 512 + t;
            int n = cid >> 3;
            int j = cid & 7;
            int idx = n * BK + ((j * 8) ^ ((n & 7) << 3));
            *reinterpret_cast<bf16x8*>(&Bs[idx]) = fB[p];
        }
        __syncthreads();

        // ---- issue next K-tile's global loads (overlap with MFMA below) ----
        if (k0 + BK < F_IN) {
            if (avalid) {
                const f32x4* s4 = reinterpret_cast<const f32x4*>(xsrc + k0 + BK);
                fA[0] = __builtin_nontemporal_load(s4 + 0);
                fA[1] = __builtin_nontemporal_load(s4 + 1);
                fA[2] = __builtin_nontemporal_load(s4 + 2);
                fA[3] = __builtin_nontemporal_load(s4 + 3);
            }
#pragma unroll
            for (int p = 0; p < 4; ++p) {
                int cid = p * 512 + t;
                int n = cid >> 3;
                int j = cid & 7;
                fB[p] = *reinterpret_cast<const bf16x8*>(wt + (size_t)n * F_IN + k0 + BK + j * 8);
            }
        }

        // ---- compute: 32 MFMA / wave / K-tile ----
#pragma unroll
        for (int kk = 0; kk < BK; kk += 32) {
            bf16x8 a[4], b[4];
#pragma unroll
            for (int m = 0; m < 4; ++m) {
                int r = wm * 64 + m * 16 + lrow;
                int idx = r * BK + ((kk + koff) ^ ((r & 7) << 3));
                a[m] = *reinterpret_cast<const bf16x8*>(&As[idx]);
            }
#pragma unroll
            for (int n = 0; n < 4; ++n) {
                int r = wn * 64 + n * 16 + lrow;
                int idx = r * BK + ((kk + koff) ^ ((r & 7) << 3));
                b[n] = *reinterpret_cast<const bf16x8*>(&Bs[idx]);
            }
#pragma unroll
            for (int m = 0; m < 4; ++m)
#pragma unroll
                for (int n = 0; n < 4; ++n)
                    acc[m][n] = __builtin_amdgcn_mfma_f32_16x16x32_bf16(a[m], b[n], acc[m][n], 0, 0, 0);
        }
        __syncthreads();
    }

    const int rbase = (lane >> 4) << 2;
#pragma unroll
    for (int m = 0; m < 4; ++m) {
#pragma unroll
        for (int r = 0; r < 4; ++r) {
            int orow = row0 + wm * 64 + m * 16 + rbase + r;
            if (orow < n_nodes) {
                ushort* dst = h + (size_t)orow * F_OUT + wn * 64 + lrow;
#pragma unroll
                for (int n = 0; n < 4; ++n) dst[n * 16] = f2bf(acc[m][n][r]);
            }
        }
    }
}

// ---------------------------------------------------------------------------
// Pass 2: one block per bucket. Concatenate the 8 sub-lists into LDS with a
// 4096-bin histogram (key = row7*32 | col>>12), padded(x8) per-row scan ->
// [beg,end) in offs/oend, zero pad slots, then counting-sort scatter: edges
// land sorted by (row, col-chunk). Col-ordering makes concurrently-resident
// rows (dispatch-ordered in spmm) walk h in a phase-coherent moving window
// -> L2/L3 gather hits. All raw data is in LDS before any global write.
// ---------------------------------------------------------------------------
__global__ __launch_bounds__(256) void bucket_sort(const int* __restrict__ bcur,
                                                   int2* __restrict__ edges,
                                                   int* __restrict__ offs,
                                                   int* __restrict__ oend,
                                                   int n_nodes) {
    __shared__ int2 raw[LDSCAP];          // 40 KB
    __shared__ int cnt[NBIN];             // 16 KB (histogram -> bin cursors)
    __shared__ int wtot;
    const int b = blockIdx.x;
    const int t = threadIdx.x;
    const size_t bbase = (size_t)b * NSUB * CAP_SUB;

    for (int i = t; i < NBIN; i += 256) cnt[i] = 0;
    __syncthreads();

    // concatenate sub-lists into LDS + histogram
    int nraw = 0;
#pragma unroll
    for (int s = 0; s < NSUB; ++s) {
        int ns = bcur[(b * NSUB + s) * CSTR];
        if (ns > CAP_SUB) ns = CAP_SUB;
        int take = ns;
        if (nraw + take > LDSCAP) take = LDSCAP - nraw;
        for (int i = t; i < take; i += 256) {
            int2 e = edges[bbase + (size_t)s * CAP_SUB + i];
            raw[nraw + i] = e;
            int key = ((e.x >> 17) << 5) | ((e.x & 0x1FFFF) >> 12);
            atomicAdd(&cnt[key], 1);
        }
        nraw += take;
    }
    __syncthreads();

    // per-row totals (32 bins each), padded(x8) exclusive scan over 128 rows
    int rowtot = 0;
    if (t < RPB) {
#pragma unroll
        for (int j = 0; j < 32; ++j) rowtot += cnt[(t << 5) + j];
    }
    int padded = (rowtot + 7) & ~7;
    int x = padded;
#pragma unroll
    for (int d = 1; d < 64; d <<= 1) {
        int y = __shfl_up(x, d, 64);
        if ((t & 63) >= d) x += y;
    }
    if (t == 63) wtot = x;                 // wave-0 total
    __syncthreads();
    if (t < RPB) {
        int rb = x - padded + ((t >= 64) ? wtot : 0);
        int gr = (b << RB_BITS) + t;
        if (gr < n_nodes) {
            offs[gr] = (int)bbase + rb;
            oend[gr] = (int)bbase + rb + padded;
        }
        for (int j = rowtot; j < padded; ++j)
            edges[bbase + rb + j] = make_int2(0, 0);
        // bin bases: cnt becomes the scatter cursor array
        int run = rb;
#pragma unroll
        for (int j = 0; j < 32; ++j) {
            int c2 = cnt[(t << 5) + j];
            cnt[(t << 5) + j] = run;
            run += c2;
        }
    }
    __syncthreads();

    // counting-sort scatter (row-major, col-chunk-ordered within row)
    for (int i = t; i < nraw; i += 256) {
        int2 e = raw[i];
        int key = ((e.x >> 17) << 5) | ((e.x & 0x1FFFF) >> 12);
        int pos = atomicAdd(&cnt[key], 1);
        edges[bbase + pos] = make_int2(e.x & 0x1FFFF, e.y);
    }
}

// ---------------------------------------------------------------------------
// Segmented SpMM + ReLU, one row per wave; lane owns 4 features (8B ushort4
// gathers, 512B/edge coalesced). Two-deep software pipeline: batch b+1's 8
// gathers issue before batch b's FMAs.
// ---------------------------------------------------------------------------
struct EB { i32x4 e0, e1, e2, e3; };
struct GB { ushort4 g0, g1, g2, g3, g4, g5, g6, g7; };

__device__ __forceinline__ void load_eb(EB& e, const int2* __restrict__ edges, int i) {
    const i32x4* ep = reinterpret_cast<const i32x4*>(edges + i);
    e.e0 = __builtin_nontemporal_load(ep + 0);
    e.e1 = __builtin_nontemporal_load(ep + 1);
    e.e2 = __builtin_nontemporal_load(ep + 2);
    e.e3 = __builtin_nontemporal_load(ep + 3);
}
__device__ __forceinline__ void issue_gb(GB& g, const EB& e, const ushort* __restrict__ hf) {
    g.g0 = *reinterpret_cast<const ushort4*>(hf + (size_t)e.e0[0] * F_OUT);
    g.g1 = *reinterpret_cast<const ushort4*>(hf + (size_t)e.e0[2] * F_OUT);
    g.g2 = *reinterpret_cast<const ushort4*>(hf + (size_t)e.e1[0] * F_OUT);
    g.g3 = *reinterpret_cast<const ushort4*>(hf + (size_t)e.e1[2] * F_OUT);
    g.g4 = *reinterpret_cast<const ushort4*>(hf + (size_t)e.e2[0] * F_OUT);
    g.g5 = *reinterpret_cast<const ushort4*>(hf + (size_t)e.e2[2] * F_OUT);
    g.g6 = *reinterpret_cast<const ushort4*>(hf + (size_t)e.e3[0] * F_OUT);
    g.g7 = *reinterpret_cast<const ushort4*>(hf + (size_t)e.e3[2] * F_OUT);
}
__device__ __forceinline__ void fma1(float* acc, float v, ushort4 g) {
    acc[0] = fmaf(v, bf2f(g.x), acc[0]);
    acc[1] = fmaf(v, bf2f(g.y), acc[1]);
    acc[2] = fmaf(v, bf2f(g.z), acc[2]);
    acc[3] = fmaf(v, bf2f(g.w), acc[3]);
}
__device__ __forceinline__ void fma_gb(float* acc, const EB& e, const GB& g) {
    fma1(acc, __int_as_float(e.e0[1]), g.g0);
    fma1(acc, __int_as_float(e.e0[3]), g.g1);
    fma1(acc, __int_as_float(e.e1[1]), g.g2);
    fma1(acc, __int_as_float(e.e1[3]), g.g3);
    fma1(acc, __int_as_float(e.e2[1]), g.g4);
    fma1(acc, __int_as_float(e.e2[3]), g.g5);
    fma1(acc, __int_as_float(e.e3[1]), g.g6);
    fma1(acc, __int_as_float(e.e3[3]), g.g7);
}

__global__ __launch_bounds__(256) void spmm_csr(const int* __restrict__ offs,
                                                const int* __restrict__ oend,
                                                const int2* __restrict__ edges,
                                                const ushort* __restrict__ h,
                                                float* __restrict__ out,
                                                int n_nodes) {
    const int row = (int)((blockIdx.x * blockDim.x + threadIdx.x) >> 6);
    if (row >= n_nodes) return;
    const int lane = threadIdx.x & 63;
    const int beg = offs[row];          // wave-uniform
    const int end = oend[row];
    const int nb = (end - beg) >> 3;    // whole batches (rows padded to x8)

    float acc[4] = {0.f, 0.f, 0.f, 0.f};
    const ushort* hf = h + lane * 4;

    if (nb > 0) {
        EB ea, eb_;
        GB ga, gb;
        load_eb(ea, edges, beg);
        issue_gb(ga, ea, hf);
        int bi = 1;
        for (; bi + 1 < nb; bi += 2) {
            load_eb(eb_, edges, beg + bi * 8);
            issue_gb(gb, eb_, hf);
            fma_gb(acc, ea, ga);
            load_eb(ea, edges, beg + (bi + 1) * 8);
            issue_gb(ga, ea, hf);
            fma_gb(acc, eb_, gb);
        }
        if (bi < nb) {
            load_eb(eb_, edges, beg + bi * 8);
            issue_gb(gb, eb_, hf);
            fma_gb(acc, ea, ga);
            fma_gb(acc, eb_, gb);
        } else {
            fma_gb(acc, ea, ga);
        }
    }

    f32x4 o;
    o[0] = fmaxf(acc[0], 0.f);
    o[1] = fmaxf(acc[1], 0.f);
    o[2] = fmaxf(acc[2], 0.f);
    o[3] = fmaxf(acc[3], 0.f);
    __builtin_nontemporal_store(o, reinterpret_cast<f32x4*>(out + (size_t)row * F_OUT + lane * 4));
}

static inline size_t align_up(size_t v, size_t a) { return (v + a - 1) & ~(a - 1); }

extern "C" void kernel_launch(void* const* d_in, const int* in_sizes, int n_in,
                              void* d_out, int out_size, void* d_ws, size_t ws_size,
                              hipStream_t stream) {
    const float* x    = (const float*)d_in[0];
    const int*   rows = (const int*)d_in[1];
    const int*   cols = (const int*)d_in[2];
    const float* vals = (const float*)d_in[3];
    const float* w    = (const float*)d_in[4];
    float* out = (float*)d_out;

    const int n_nodes = in_sizes[0] / F_IN;
    const int n_edges = in_sizes[1];
    const int nbuck_used = (n_nodes + RPB - 1) >> RB_BITS;

    // ---- workspace layout (~120 MB) ----
    char* ws = (char*)d_ws;
    size_t off = 0;
    ushort* h   = (ushort*)(ws + off); off = align_up(off + (size_t)n_nodes * F_OUT * 2, 256);
    ushort* wt  = (ushort*)(ws + off); off = align_up(off + (size_t)F_OUT * F_IN * 2, 256);
    int2* edges = (int2*)(ws + off);   off = align_up(off + (size_t)NBUCK * NSUB * CAP_SUB * 8, 256);
    int* offs   = (int*)(ws + off);    off = align_up(off + (size_t)n_nodes * 4, 256);
    int* oend   = (int*)(ws + off);    off = align_up(off + (size_t)n_nodes * 4, 256);
    int* bcur   = (int*)(ws + off);    off = align_up(off + (size_t)NBUCK * NSUB * CSTR * 4, 256);
    (void)ws_size;

    // 1) Wt = bf16(W^T)
    conv_w<<<(F_IN * F_OUT) / 256, 256, 0, stream>>>(w, wt);
    hipMemsetAsync(bcur, 0, (size_t)NBUCK * NSUB * CSTR * 4, stream);

    // 2) FUSED: h = bf16(x @ W) (MFMA) + bucket_place, interleaved 1:2
    const int ngemm  = (n_nodes + BM - 1) / BM;            // 782
    const int nplace = (n_edges + 2047) / 2048;            // 1563 (512 thr x 4 edges)
    gemm_place<<<ngemm + nplace, 512, 0, stream>>>(x, wt, h, n_nodes,
                                                   rows, cols, vals, bcur, edges,
                                                   n_edges, ngemm);

    // 3) bucket sort: row-major + col-chunk-ordered within row
    bucket_sort<<<nbuck_used, 256, 0, stream>>>(bcur, edges, offs, oend, n_nodes);

    // 4) segmented SpMM + ReLU (1 row/wave, 2-deep gather pipeline)
    spmm_csr<<<(n_nodes * 64 + 255) / 256, 256, 0, stream>>>(offs, oend, edges, h, out, n_nodes);
}